// Round 3
// baseline (1481.141 us; speedup 1.0000x reference)
//
#include <hip/hip_runtime.h>
#include <hip/hip_bf16.h>

#define DIMK 3
#define NPTS 30
#define KK   181
#define PP   24360
#define DEMB 190
#define VLD  192   // padded vec row stride (floats)

// ---------------------------------------------------------------------------
// Kernel 1: per-permutation inner embed -> vec (PP x VLD)
// ---------------------------------------------------------------------------
__global__ __launch_bounds__(256) void k_inner(
    const float* __restrict__ M,      // 3 x 30
    const float* __restrict__ Ws_in,  // 181 x 3
    const float* __restrict__ Wd_in,  // 181 x 27
    float* __restrict__ vec)          // PP x VLD
{
    __shared__ float Gs[NPTS * NPTS];       // 900
    __shared__ float WsS[KK * 3];           // 543
    __shared__ float WdS[KK * 27];          // 4887

    const int tid = threadIdx.x;

    for (int i = tid; i < KK * 3; i += 256)  WsS[i] = Ws_in[i];
    for (int i = tid; i < KK * 27; i += 256) WdS[i] = Wd_in[i];
    for (int e = tid; e < NPTS * NPTS; e += 256) {
        int a = e / NPTS, b = e % NPTS;
        Gs[e] = M[a] * M[b] + M[NPTS + a] * M[NPTS + b] + M[2 * NPTS + a] * M[2 * NPTS + b];
    }
    __syncthreads();

    const int wave = tid >> 6;
    const int lane = tid & 63;
    const int p = blockIdx.x * 4 + wave;

    // factorial-number-system decode of itertools.permutations(range(30),3)
    int i0 = p / 812;            // 812 = 29*28
    int r  = p - i0 * 812;
    int i1 = r / 28;
    int i2 = r - i1 * 28;
    int c0 = i0;
    int c1 = i1 + (i1 >= c0 ? 1 : 0);
    int lo = min(c0, c1), hi = max(c0, c1);
    int c2 = i2;
    if (c2 >= lo) c2++;
    if (c2 >= hi) c2++;

    float* vrow = vec + (long)p * VLD;

    if (lane < 9) {
        int i = lane / 3, j = lane % 3;
        int ci = (i == 0) ? c0 : ((i == 1) ? c1 : c2);
        int cj = (j == 0) ? c0 : ((j == 1) ? c1 : c2);
        vrow[lane] = Gs[ci * NPTS + cj];
    }

    const float* g0 = Gs + c0 * NPTS;
    const float* g1 = Gs + c1 * NPTS;
    const float* g2 = Gs + c2 * NPTS;
    const float INF = __builtin_inff();

    for (int it = 0; it < 3; ++it) {
        int k = it * 64 + lane;
        if (k < KK) {
            float w0 = WsS[k * 3 + 0], w1 = WsS[k * 3 + 1], w2 = WsS[k * 3 + 2];
            float v[32];
#pragma unroll
            for (int j = 0; j < NPTS; ++j) {
                float val = w0 * g0[j] + w1 * g1[j] + w2 * g2[j];
                bool excl = (j == c0) | (j == c1) | (j == c2);
                v[j] = excl ? INF : val;
            }
            v[30] = INF;
            v[31] = INF;

#pragma unroll
            for (int sz = 2; sz <= 32; sz <<= 1) {
#pragma unroll
                for (int st = sz >> 1; st >= 1; st >>= 1) {
#pragma unroll
                    for (int i = 0; i < 32; ++i) {
                        int j = i ^ st;
                        if (j > i) {
                            bool up = ((i & sz) == 0);
                            float a = v[i], b = v[j];
                            float mn = fminf(a, b), mx = fmaxf(a, b);
                            v[i] = up ? mn : mx;
                            v[j] = up ? mx : mn;
                        }
                    }
                }
            }

            float emb = 0.f;
#pragma unroll
            for (int m = 0; m < 27; ++m) emb += WdS[k * 27 + m] * v[m];
            vrow[9 + k] = emb;
        } else if (k < 183) {
            vrow[9 + k] = 0.f;
        }
    }
}

// ---------------------------------------------------------------------------
// Kernel 2: sm2T[k][p] = dot(vec[p][0:190], Ws_out[k][0:190])
// ---------------------------------------------------------------------------
#define BP  64
#define BK  64
#define DC  96
#define LDT 97

__global__ __launch_bounds__(256) void k_gemm(
    const float* __restrict__ vec,    // PP x VLD
    const float* __restrict__ Wout,   // 181 x 190
    float* __restrict__ sm2T)         // 181 x PP
{
    __shared__ float As[BP * LDT];
    __shared__ float Bs[BK * LDT];

    const int tid = threadIdx.x;
    const int pTile = blockIdx.x * BP;
    const int kTile = blockIdx.y * BK;
    const int tx = tid & 15;
    const int ty = tid >> 4;

    float acc[4][4];
#pragma unroll
    for (int i = 0; i < 4; ++i)
#pragma unroll
        for (int j = 0; j < 4; ++j) acc[i][j] = 0.f;

    for (int ch = 0; ch < 2; ++ch) {
        const int dbase = ch * DC;
        __syncthreads();
        for (int e = tid; e < BP * DC; e += 256) {
            int pl = e / DC, d = e - pl * DC;
            int pg = pTile + pl;
            As[pl * LDT + d] = (pg < PP) ? vec[(long)pg * VLD + dbase + d] : 0.f;
        }
        for (int e = tid; e < BK * DC; e += 256) {
            int kl = e / DC, d = e - kl * DC;
            int kg = kTile + kl;
            int dg = dbase + d;
            Bs[kl * LDT + d] = (kg < KK && dg < DEMB) ? Wout[kg * DEMB + dg] : 0.f;
        }
        __syncthreads();

        for (int d = 0; d < DC; ++d) {
            float a[4], b[4];
#pragma unroll
            for (int i = 0; i < 4; ++i) a[i] = As[(tx + 16 * i) * LDT + d];
#pragma unroll
            for (int j = 0; j < 4; ++j) b[j] = Bs[(ty + 16 * j) * LDT + d];
#pragma unroll
            for (int i = 0; i < 4; ++i)
#pragma unroll
                for (int j = 0; j < 4; ++j) acc[i][j] += a[i] * b[j];
        }
    }

#pragma unroll
    for (int j = 0; j < 4; ++j) {
        int kg = kTile + ty + 16 * j;
        if (kg < KK) {
#pragma unroll
            for (int i = 0; i < 4; ++i) {
                int pg = pTile + tx + 16 * i;
                if (pg < PP) sm2T[(long)kg * PP + pg] = acc[i][j];
            }
        }
    }
}

// ---------------------------------------------------------------------------
// Kernel 3: per-k LSD radix sort (4 x 8-bit) of the 24360-column, keys held
// in registers (24/thread), one 96 KiB LDS scatter buffer + 16 KiB per-wave
// histograms. Stable via wave-contiguous chunks + match_any lane ranking.
// __launch_bounds__(1024,4): 1 block/CU (LDS forces this anyway) -> 128 VGPR
// budget so key[24] does NOT spill to scratch (round-2 failure mode: 3.2 GB
// of scratch traffic at VGPR=64).
// ---------------------------------------------------------------------------
#define SN     24576            // padded to 1024*24
#define WAVES  16
#define WCHUNK 1536             // SN / WAVES
#define CPT    24               // keys per thread (= iterations per wave)

__device__ __forceinline__ unsigned long long matchany8(unsigned d) {
    unsigned long long m = ~0ull;
#pragma unroll
    for (int b = 0; b < 8; ++b) {
        unsigned bit = (d >> b) & 1u;
        unsigned long long bal = __ballot(bit);
        m &= bit ? bal : ~bal;
    }
    return m;
}

__global__ __launch_bounds__(1024, 4) void k_sort(
    const float* __restrict__ sm2T,   // 181 x PP
    const float* __restrict__ WdOut,  // 181 x PP
    float* __restrict__ out)          // 181
{
    __shared__ unsigned keys[SN];           // 96 KiB scatter buffer
    __shared__ unsigned cnt[WAVES * 256];   // 16 KiB per-wave histograms
    __shared__ unsigned tot[256];
    __shared__ float red[WAVES];

    const int tid  = threadIdx.x;
    const int wave = tid >> 6;
    const int lane = tid & 63;
    const int k    = blockIdx.x;
    const float* col = sm2T + (long)k * PP;

    const int base_idx = wave * WCHUNK + lane;
    const unsigned long long lt_mask = (1ull << lane) - 1ull;

    // load + encode to monotone u32 keys (registers)
    unsigned key[CPT];
#pragma unroll
    for (int j = 0; j < CPT; ++j) {
        int idx = base_idx + j * 64;
        unsigned u;
        if (idx < PP) {
            unsigned raw = __float_as_uint(col[idx]);
            u = (raw & 0x80000000u) ? ~raw : (raw | 0x80000000u);
        } else {
            u = 0xFFFFFFFFu;   // pad sorts last
        }
        key[j] = u;
    }

    for (int pass = 0; pass < 4; ++pass) {
        const int sh = pass * 8;

        // zero histograms
        for (int i = tid; i < WAVES * 256; i += 1024) cnt[i] = 0;
        __syncthreads();

        // phase 1: per-wave digit counts (leader adds group size)
#pragma unroll
        for (int j = 0; j < CPT; ++j) {
            unsigned d = (key[j] >> sh) & 255u;
            unsigned long long m = matchany8(d);
            int leader = __ffsll((unsigned long long)m) - 1;
            if (lane == leader)
                atomicAdd(&cnt[wave * 256 + d], (unsigned)__popcll(m));
        }
        __syncthreads();

        // phase 2a: per-digit exclusive prefix across waves
        if (tid < 256) {
            unsigned run = 0;
            for (int w = 0; w < WAVES; ++w) {
                unsigned t = cnt[w * 256 + tid];
                cnt[w * 256 + tid] = run;
                run += t;
            }
            tot[tid] = run;
        }
        __syncthreads();

        // phase 2b: inclusive scan over tot[256] (Hillis-Steele)
        for (int off = 1; off < 256; off <<= 1) {
            unsigned v = 0;
            if (tid < 256 && tid >= off) v = tot[tid - off];
            __syncthreads();
            if (tid < 256) tot[tid] += v;
            __syncthreads();
        }

        // phase 2c: cnt[w][d] += exclusive digit base
        for (int i = tid; i < WAVES * 256; i += 1024) {
            int d = i & 255;
            unsigned db = (d == 0) ? 0u : tot[d - 1];
            cnt[i] += db;
        }
        __syncthreads();

        // phase 3: rank & scatter (stable: iteration-major, lane-minor order)
#pragma unroll
        for (int j = 0; j < CPT; ++j) {
            unsigned d = (key[j] >> sh) & 255u;
            unsigned long long m = matchany8(d);
            int leader = __ffsll((unsigned long long)m) - 1;
            unsigned myrank = (unsigned)__popcll(m & lt_mask);
            unsigned old = 0;
            if (lane == leader)
                old = atomicAdd(&cnt[wave * 256 + d], (unsigned)__popcll(m));
            old = __shfl(old, leader, 64);
            keys[old + myrank] = key[j];
        }
        __syncthreads();

        // phase 4: gather back to registers in fixed traversal order
#pragma unroll
        for (int j = 0; j < CPT; ++j) key[j] = keys[base_idx + j * 64];
        __syncthreads();
    }

    // keys[] in LDS now holds the fully sorted column (pads at the end).
    const float* wrow = WdOut + (long)k * PP;
    float local = 0.f;
    for (int r = tid; r < PP; r += 1024) {
        unsigned u = keys[r];
        unsigned raw = (u & 0x80000000u) ? (u & 0x7FFFFFFFu) : ~u;
        local += wrow[r] * __uint_as_float(raw);
    }

#pragma unroll
    for (int off = 32; off > 0; off >>= 1)
        local += __shfl_down(local, off, 64);
    if (lane == 0) red[wave] = local;
    __syncthreads();
    if (tid < WAVES) {
        float x = red[tid];
#pragma unroll
        for (int off = 8; off > 0; off >>= 1)
            x += __shfl_down(x, off, 64);
        if (tid == 0) out[k] = x;
    }
}

// ---------------------------------------------------------------------------
extern "C" void kernel_launch(void* const* d_in, const int* in_sizes, int n_in,
                              void* d_out, int out_size, void* d_ws, size_t ws_size,
                              hipStream_t stream) {
    const float* M      = (const float*)d_in[0];
    const float* Ws_in  = (const float*)d_in[1];
    const float* Wd_in  = (const float*)d_in[2];
    const float* Ws_out = (const float*)d_in[3];
    const float* Wd_out = (const float*)d_in[4];
    float* out = (float*)d_out;

    float* vec  = (float*)d_ws;                    // PP*VLD floats = 18.7 MB
    float* sm2T = vec + (size_t)PP * VLD;          // KK*PP floats  = 17.6 MB

    k_inner<<<PP / 4, 256, 0, stream>>>(M, Ws_in, Wd_in, vec);

    dim3 g2((PP + BP - 1) / BP, (KK + BK - 1) / BK);
    k_gemm<<<g2, 256, 0, stream>>>(vec, Ws_out, sm2T);

    k_sort<<<KK, 1024, 0, stream>>>(sm2T, Wd_out, out);
}

// Round 4
// 1462.093 us; speedup vs baseline: 1.0130x; 1.0130x over previous
//
#include <hip/hip_runtime.h>
#include <hip/hip_bf16.h>

#define DIMK 3
#define NPTS 30
#define KK   181
#define PP   24360
#define DEMB 190
#define VLD  192   // padded vec row stride (floats)

// ---------------------------------------------------------------------------
// Kernel 1: per-permutation inner embed -> vec (PP x VLD)
// ---------------------------------------------------------------------------
__global__ __launch_bounds__(256) void k_inner(
    const float* __restrict__ M,      // 3 x 30
    const float* __restrict__ Ws_in,  // 181 x 3
    const float* __restrict__ Wd_in,  // 181 x 27
    float* __restrict__ vec)          // PP x VLD
{
    __shared__ float Gs[NPTS * NPTS];       // 900
    __shared__ float WsS[KK * 3];           // 543
    __shared__ float WdS[KK * 27];          // 4887

    const int tid = threadIdx.x;

    for (int i = tid; i < KK * 3; i += 256)  WsS[i] = Ws_in[i];
    for (int i = tid; i < KK * 27; i += 256) WdS[i] = Wd_in[i];
    for (int e = tid; e < NPTS * NPTS; e += 256) {
        int a = e / NPTS, b = e % NPTS;
        Gs[e] = M[a] * M[b] + M[NPTS + a] * M[NPTS + b] + M[2 * NPTS + a] * M[2 * NPTS + b];
    }
    __syncthreads();

    const int wave = tid >> 6;
    const int lane = tid & 63;
    const int p = blockIdx.x * 4 + wave;

    // factorial-number-system decode of itertools.permutations(range(30),3)
    int i0 = p / 812;            // 812 = 29*28
    int r  = p - i0 * 812;
    int i1 = r / 28;
    int i2 = r - i1 * 28;
    int c0 = i0;
    int c1 = i1 + (i1 >= c0 ? 1 : 0);
    int lo = min(c0, c1), hi = max(c0, c1);
    int c2 = i2;
    if (c2 >= lo) c2++;
    if (c2 >= hi) c2++;

    float* vrow = vec + (long)p * VLD;

    if (lane < 9) {
        int i = lane / 3, j = lane % 3;
        int ci = (i == 0) ? c0 : ((i == 1) ? c1 : c2);
        int cj = (j == 0) ? c0 : ((j == 1) ? c1 : c2);
        vrow[lane] = Gs[ci * NPTS + cj];
    }

    const float* g0 = Gs + c0 * NPTS;
    const float* g1 = Gs + c1 * NPTS;
    const float* g2 = Gs + c2 * NPTS;
    const float INF = __builtin_inff();

    for (int it = 0; it < 3; ++it) {
        int k = it * 64 + lane;
        if (k < KK) {
            float w0 = WsS[k * 3 + 0], w1 = WsS[k * 3 + 1], w2 = WsS[k * 3 + 2];
            float v[32];
#pragma unroll
            for (int j = 0; j < NPTS; ++j) {
                float val = w0 * g0[j] + w1 * g1[j] + w2 * g2[j];
                bool excl = (j == c0) | (j == c1) | (j == c2);
                v[j] = excl ? INF : val;
            }
            v[30] = INF;
            v[31] = INF;

#pragma unroll
            for (int sz = 2; sz <= 32; sz <<= 1) {
#pragma unroll
                for (int st = sz >> 1; st >= 1; st >>= 1) {
#pragma unroll
                    for (int i = 0; i < 32; ++i) {
                        int j = i ^ st;
                        if (j > i) {
                            bool up = ((i & sz) == 0);
                            float a = v[i], b = v[j];
                            float mn = fminf(a, b), mx = fmaxf(a, b);
                            v[i] = up ? mn : mx;
                            v[j] = up ? mx : mn;
                        }
                    }
                }
            }

            float emb = 0.f;
#pragma unroll
            for (int m = 0; m < 27; ++m) emb += WdS[k * 27 + m] * v[m];
            vrow[9 + k] = emb;
        } else if (k < 183) {
            vrow[9 + k] = 0.f;
        }
    }
}

// ---------------------------------------------------------------------------
// Kernel 2: sm2T[k][p] = dot(vec[p][0:190], Ws_out[k][0:190])
// ---------------------------------------------------------------------------
#define BP  64
#define BK  64
#define DC  96
#define LDT 97

__global__ __launch_bounds__(256) void k_gemm(
    const float* __restrict__ vec,    // PP x VLD
    const float* __restrict__ Wout,   // 181 x 190
    float* __restrict__ sm2T)         // 181 x PP
{
    __shared__ float As[BP * LDT];
    __shared__ float Bs[BK * LDT];

    const int tid = threadIdx.x;
    const int pTile = blockIdx.x * BP;
    const int kTile = blockIdx.y * BK;
    const int tx = tid & 15;
    const int ty = tid >> 4;

    float acc[4][4];
#pragma unroll
    for (int i = 0; i < 4; ++i)
#pragma unroll
        for (int j = 0; j < 4; ++j) acc[i][j] = 0.f;

    for (int ch = 0; ch < 2; ++ch) {
        const int dbase = ch * DC;
        __syncthreads();
        for (int e = tid; e < BP * DC; e += 256) {
            int pl = e / DC, d = e - pl * DC;
            int pg = pTile + pl;
            As[pl * LDT + d] = (pg < PP) ? vec[(long)pg * VLD + dbase + d] : 0.f;
        }
        for (int e = tid; e < BK * DC; e += 256) {
            int kl = e / DC, d = e - kl * DC;
            int kg = kTile + kl;
            int dg = dbase + d;
            Bs[kl * LDT + d] = (kg < KK && dg < DEMB) ? Wout[kg * DEMB + dg] : 0.f;
        }
        __syncthreads();

        for (int d = 0; d < DC; ++d) {
            float a[4], b[4];
#pragma unroll
            for (int i = 0; i < 4; ++i) a[i] = As[(tx + 16 * i) * LDT + d];
#pragma unroll
            for (int j = 0; j < 4; ++j) b[j] = Bs[(ty + 16 * j) * LDT + d];
#pragma unroll
            for (int i = 0; i < 4; ++i)
#pragma unroll
                for (int j = 0; j < 4; ++j) acc[i][j] += a[i] * b[j];
        }
    }

#pragma unroll
    for (int j = 0; j < 4; ++j) {
        int kg = kTile + ty + 16 * j;
        if (kg < KK) {
#pragma unroll
            for (int i = 0; i < 4; ++i) {
                int pg = pTile + tx + 16 * i;
                if (pg < PP) sm2T[(long)kg * PP + pg] = acc[i][j];
            }
        }
    }
}

// ---------------------------------------------------------------------------
// Kernel 3: per-k LSD radix sort (4 x 8-bit), 24 keys/thread held in 24
// INDIVIDUALLY-NAMED registers (macro-expanded) so the compiler cannot demote
// them to scratch (round-2/3 failure: private-array demotion -> 3.2 GB of
// uncoalesced scratch traffic at 2.6 TB/s). One 96 KiB LDS scatter buffer +
// 16 KiB per-wave histograms. Stable via wave-contiguous chunks + match_any.
// ---------------------------------------------------------------------------
#define SN     24576            // padded to 1024*24
#define WAVES  16
#define WCHUNK 1536             // SN / WAVES
#define CPT    24               // keys per thread

#define REPEAT24(F) F(0) F(1) F(2) F(3) F(4) F(5) F(6) F(7) F(8) F(9) F(10) F(11) \
                    F(12) F(13) F(14) F(15) F(16) F(17) F(18) F(19) F(20) F(21) F(22) F(23)

__device__ __forceinline__ unsigned long long matchany8(unsigned d) {
    unsigned long long m = ~0ull;
#pragma unroll
    for (int b = 0; b < 8; ++b) {
        unsigned bit = (d >> b) & 1u;
        unsigned long long bal = __ballot(bit);
        m &= bit ? bal : ~bal;
    }
    return m;
}

__global__ __launch_bounds__(1024, 4) void k_sort(
    const float* __restrict__ sm2T,   // 181 x PP
    const float* __restrict__ WdOut,  // 181 x PP
    float* __restrict__ out)          // 181
{
    __shared__ unsigned keys[SN];           // 96 KiB scatter buffer
    __shared__ unsigned cnt[WAVES * 256];   // 16 KiB per-wave histograms
    __shared__ unsigned tot[256];
    __shared__ float red[WAVES];

    const int tid  = threadIdx.x;
    const int wave = tid >> 6;
    const int lane = tid & 63;
    const int k    = blockIdx.x;
    const float* col = sm2T + (long)k * PP;

    const int base_idx = wave * WCHUNK + lane;
    const int wbase = wave * 256;
    const unsigned long long lt_mask = (1ull << lane) - 1ull;

    // 24 named key registers (cannot be demoted to scratch)
#define DECLK(j) unsigned key##j;
    REPEAT24(DECLK)
#undef DECLK

    // load + encode to monotone u32 keys
#define INITK(j) { int idx = base_idx + (j) * 64; unsigned u; \
    if (idx < PP) { unsigned raw = __float_as_uint(col[idx]); \
        u = (raw & 0x80000000u) ? ~raw : (raw | 0x80000000u); } \
    else u = 0xFFFFFFFFu; \
    key##j = u; }
    REPEAT24(INITK)
#undef INITK

    for (int pass = 0; pass < 4; ++pass) {
        const int sh = pass * 8;

        // zero histograms
        for (int i = tid; i < WAVES * 256; i += 1024) cnt[i] = 0;
        __syncthreads();

        // phase 1: per-wave digit counts (leader adds group size)
#define P1(j) { unsigned d = (key##j >> sh) & 255u; \
    unsigned long long m = matchany8(d); \
    int leader = __ffsll((unsigned long long)m) - 1; \
    if (lane == leader) atomicAdd(&cnt[wbase + d], (unsigned)__popcll(m)); }
        REPEAT24(P1)
#undef P1
        __syncthreads();

        // phase 2a: per-digit exclusive prefix across waves
        if (tid < 256) {
            unsigned run = 0;
            for (int w = 0; w < WAVES; ++w) {
                unsigned t = cnt[w * 256 + tid];
                cnt[w * 256 + tid] = run;
                run += t;
            }
            tot[tid] = run;
        }
        __syncthreads();

        // phase 2b: inclusive scan over tot[256] (Hillis-Steele)
        for (int off = 1; off < 256; off <<= 1) {
            unsigned v = 0;
            if (tid < 256 && tid >= off) v = tot[tid - off];
            __syncthreads();
            if (tid < 256) tot[tid] += v;
            __syncthreads();
        }

        // phase 2c: cnt[w][d] += exclusive digit base
        for (int i = tid; i < WAVES * 256; i += 1024) {
            int d = i & 255;
            unsigned db = (d == 0) ? 0u : tot[d - 1];
            cnt[i] += db;
        }
        __syncthreads();

        // phase 3: rank & scatter (stable: j-major, lane-minor order)
#define P3(j) { unsigned d = (key##j >> sh) & 255u; \
    unsigned long long m = matchany8(d); \
    int leader = __ffsll((unsigned long long)m) - 1; \
    unsigned myrank = (unsigned)__popcll(m & lt_mask); \
    unsigned old = 0; \
    if (lane == leader) old = atomicAdd(&cnt[wbase + d], (unsigned)__popcll(m)); \
    old = __shfl(old, leader, 64); \
    keys[old + myrank] = key##j; }
        REPEAT24(P3)
#undef P3
        __syncthreads();

        // phase 4: gather back to registers in fixed traversal order
#define P4(j) key##j = keys[base_idx + (j) * 64];
        REPEAT24(P4)
#undef P4
        __syncthreads();
    }

    // keys[] in LDS now holds the fully sorted column (pads at the end).
    const float* wrow = WdOut + (long)k * PP;
    float local = 0.f;
    for (int r = tid; r < PP; r += 1024) {
        unsigned u = keys[r];
        unsigned raw = (u & 0x80000000u) ? (u & 0x7FFFFFFFu) : ~u;
        local += wrow[r] * __uint_as_float(raw);
    }

#pragma unroll
    for (int off = 32; off > 0; off >>= 1)
        local += __shfl_down(local, off, 64);
    if (lane == 0) red[wave] = local;
    __syncthreads();
    if (tid < WAVES) {
        float x = red[tid];
#pragma unroll
        for (int off = 8; off > 0; off >>= 1)
            x += __shfl_down(x, off, 64);
        if (tid == 0) out[k] = x;
    }
}

// ---------------------------------------------------------------------------
extern "C" void kernel_launch(void* const* d_in, const int* in_sizes, int n_in,
                              void* d_out, int out_size, void* d_ws, size_t ws_size,
                              hipStream_t stream) {
    const float* M      = (const float*)d_in[0];
    const float* Ws_in  = (const float*)d_in[1];
    const float* Wd_in  = (const float*)d_in[2];
    const float* Ws_out = (const float*)d_in[3];
    const float* Wd_out = (const float*)d_in[4];
    float* out = (float*)d_out;

    float* vec  = (float*)d_ws;                    // PP*VLD floats = 18.7 MB
    float* sm2T = vec + (size_t)PP * VLD;          // KK*PP floats  = 17.6 MB

    k_inner<<<PP / 4, 256, 0, stream>>>(M, Ws_in, Wd_in, vec);

    dim3 g2((PP + BP - 1) / BP, (KK + BK - 1) / BK);
    k_gemm<<<g2, 256, 0, stream>>>(vec, Ws_out, sm2T);

    k_sort<<<KK, 1024, 0, stream>>>(sm2T, Wd_out, out);
}

// Round 6
// 429.334 us; speedup vs baseline: 3.4499x; 3.4055x over previous
//
#include <hip/hip_runtime.h>
#include <hip/hip_bf16.h>

#define DIMK 3
#define NPTS 30
#define KK   181
#define PP   24360
#define DEMB 190
#define VLD  192   // padded vec row stride (floats)

// ---------------------------------------------------------------------------
// Kernel 1: per-permutation inner embed -> vec (PP x VLD)
// ---------------------------------------------------------------------------
__global__ __launch_bounds__(256) void k_inner(
    const float* __restrict__ M,      // 3 x 30
    const float* __restrict__ Ws_in,  // 181 x 3
    const float* __restrict__ Wd_in,  // 181 x 27
    float* __restrict__ vec)          // PP x VLD
{
    __shared__ float Gs[NPTS * NPTS];       // 900
    __shared__ float WsS[KK * 3];           // 543
    __shared__ float WdS[KK * 27];          // 4887

    const int tid = threadIdx.x;

    for (int i = tid; i < KK * 3; i += 256)  WsS[i] = Ws_in[i];
    for (int i = tid; i < KK * 27; i += 256) WdS[i] = Wd_in[i];
    for (int e = tid; e < NPTS * NPTS; e += 256) {
        int a = e / NPTS, b = e % NPTS;
        Gs[e] = M[a] * M[b] + M[NPTS + a] * M[NPTS + b] + M[2 * NPTS + a] * M[2 * NPTS + b];
    }
    __syncthreads();

    const int wave = tid >> 6;
    const int lane = tid & 63;
    const int p = blockIdx.x * 4 + wave;

    // factorial-number-system decode of itertools.permutations(range(30),3)
    int i0 = p / 812;            // 812 = 29*28
    int r  = p - i0 * 812;
    int i1 = r / 28;
    int i2 = r - i1 * 28;
    int c0 = i0;
    int c1 = i1 + (i1 >= c0 ? 1 : 0);
    int lo = min(c0, c1), hi = max(c0, c1);
    int c2 = i2;
    if (c2 >= lo) c2++;
    if (c2 >= hi) c2++;

    float* vrow = vec + (long)p * VLD;

    if (lane < 9) {
        int i = lane / 3, j = lane % 3;
        int ci = (i == 0) ? c0 : ((i == 1) ? c1 : c2);
        int cj = (j == 0) ? c0 : ((j == 1) ? c1 : c2);
        vrow[lane] = Gs[ci * NPTS + cj];
    }

    const float* g0 = Gs + c0 * NPTS;
    const float* g1 = Gs + c1 * NPTS;
    const float* g2 = Gs + c2 * NPTS;
    const float INF = __builtin_inff();

    for (int it = 0; it < 3; ++it) {
        int k = it * 64 + lane;
        if (k < KK) {
            float w0 = WsS[k * 3 + 0], w1 = WsS[k * 3 + 1], w2 = WsS[k * 3 + 2];
            float v[32];
#pragma unroll
            for (int j = 0; j < NPTS; ++j) {
                float val = w0 * g0[j] + w1 * g1[j] + w2 * g2[j];
                bool excl = (j == c0) | (j == c1) | (j == c2);
                v[j] = excl ? INF : val;
            }
            v[30] = INF;
            v[31] = INF;

#pragma unroll
            for (int sz = 2; sz <= 32; sz <<= 1) {
#pragma unroll
                for (int st = sz >> 1; st >= 1; st >>= 1) {
#pragma unroll
                    for (int i = 0; i < 32; ++i) {
                        int j = i ^ st;
                        if (j > i) {
                            bool up = ((i & sz) == 0);
                            float a = v[i], b = v[j];
                            float mn = fminf(a, b), mx = fmaxf(a, b);
                            v[i] = up ? mn : mx;
                            v[j] = up ? mx : mn;
                        }
                    }
                }
            }

            float emb = 0.f;
#pragma unroll
            for (int m = 0; m < 27; ++m) emb += WdS[k * 27 + m] * v[m];
            vrow[9 + k] = emb;
        } else if (k < 183) {
            vrow[9 + k] = 0.f;
        }
    }
}

// ---------------------------------------------------------------------------
// Kernel 2: sm2T[k][p] = dot(vec[p][0:190], Ws_out[k][0:190])
// ---------------------------------------------------------------------------
#define BP  64
#define BK  64
#define DC  96
#define LDT 97

__global__ __launch_bounds__(256) void k_gemm(
    const float* __restrict__ vec,    // PP x VLD
    const float* __restrict__ Wout,   // 181 x 190
    float* __restrict__ sm2T)         // 181 x PP
{
    __shared__ float As[BP * LDT];
    __shared__ float Bs[BK * LDT];

    const int tid = threadIdx.x;
    const int pTile = blockIdx.x * BP;
    const int kTile = blockIdx.y * BK;
    const int tx = tid & 15;
    const int ty = tid >> 4;

    float acc[4][4];
#pragma unroll
    for (int i = 0; i < 4; ++i)
#pragma unroll
        for (int j = 0; j < 4; ++j) acc[i][j] = 0.f;

    for (int ch = 0; ch < 2; ++ch) {
        const int dbase = ch * DC;
        __syncthreads();
        for (int e = tid; e < BP * DC; e += 256) {
            int pl = e / DC, d = e - pl * DC;
            int pg = pTile + pl;
            As[pl * LDT + d] = (pg < PP) ? vec[(long)pg * VLD + dbase + d] : 0.f;
        }
        for (int e = tid; e < BK * DC; e += 256) {
            int kl = e / DC, d = e - kl * DC;
            int kg = kTile + kl;
            int dg = dbase + d;
            Bs[kl * LDT + d] = (kg < KK && dg < DEMB) ? Wout[kg * DEMB + dg] : 0.f;
        }
        __syncthreads();

        for (int d = 0; d < DC; ++d) {
            float a[4], b[4];
#pragma unroll
            for (int i = 0; i < 4; ++i) a[i] = As[(tx + 16 * i) * LDT + d];
#pragma unroll
            for (int j = 0; j < 4; ++j) b[j] = Bs[(ty + 16 * j) * LDT + d];
#pragma unroll
            for (int i = 0; i < 4; ++i)
#pragma unroll
                for (int j = 0; j < 4; ++j) acc[i][j] += a[i] * b[j];
        }
    }

#pragma unroll
    for (int j = 0; j < 4; ++j) {
        int kg = kTile + ty + 16 * j;
        if (kg < KK) {
#pragma unroll
            for (int i = 0; i < 4; ++i) {
                int pg = pTile + tx + 16 * i;
                if (pg < PP) sm2T[(long)kg * PP + pg] = acc[i][j];
            }
        }
    }
}

// ---------------------------------------------------------------------------
// Kernel 3: per-k LSD radix sort (4 x 8-bit), zero per-thread persistent
// state, keys ping-pong between global buffers (sm2T row k and scratch
// overlaying dead vec). Round-5 bug fixed: ALL 64 lanes always execute the
// ballots; validity is a 9th digit bit so pad lanes (tail: PP % WCHUNK != 0)
// form their own match group and never contaminate real digit groups.
// ---------------------------------------------------------------------------
#define WAVES  16
#define WCHUNK 1536             // 64 lanes * 24 iters

__device__ __forceinline__ unsigned long long matchany9(unsigned d) {
    unsigned long long m = ~0ull;
#pragma unroll
    for (int b = 0; b < 9; ++b) {
        unsigned bit = (d >> b) & 1u;
        unsigned long long bal = __ballot(bit);
        m &= bit ? bal : ~bal;
    }
    return m;
}

__global__ __launch_bounds__(1024) void k_sort(
    float* sm2T,              // 181 x PP (row k is mutated: reused as ping buffer)
    unsigned* bufA,           // 181 x PP scratch (pong buffer, overlays dead vec)
    const float* __restrict__ WdOut,  // 181 x PP
    float* __restrict__ out)          // 181
{
    __shared__ unsigned cnt[WAVES * 256];   // 16 KiB per-wave histograms
    __shared__ unsigned tot[256];
    __shared__ float red[WAVES];

    const int tid  = threadIdx.x;
    const int wave = tid >> 6;
    const int lane = tid & 63;
    const int k    = blockIdx.x;

    unsigned* rowU = (unsigned*)sm2T + (long)k * PP;   // float bits, then keys
    unsigned* bA   = bufA + (long)k * PP;

    const int base_idx = wave * WCHUNK + lane;
    const int wbase = wave * 256;
    const unsigned long long lt_mask = (1ull << lane) - 1ull;

    for (int pass = 0; pass < 4; ++pass) {
        const int sh = pass * 8;
        const bool enc = (pass == 0);
        const unsigned* src = (pass & 1) ? bA : rowU;
        unsigned* dst       = (pass & 1) ? rowU : bA;

        // zero histograms
        for (int i = tid; i < WAVES * 256; i += 1024) cnt[i] = 0;
        __syncthreads();

        // phase 1: per-wave digit counts (coalesced global re-read).
        // All lanes ballot; invalid lanes carry digit-bit-8 so they match
        // only each other.
        for (int j = 0; j < 24; ++j) {
            int idx = base_idx + j * 64;
            bool valid = (idx < PP);
            unsigned u = valid ? src[idx] : 0u;
            if (enc) u = (u & 0x80000000u) ? ~u : (u | 0x80000000u);
            unsigned d9 = ((u >> sh) & 255u) | (valid ? 0u : 256u);
            unsigned long long m = matchany9(d9);
            if (valid) {
                int leader = __ffsll(m) - 1;
                if (lane == leader)
                    atomicAdd(&cnt[wbase + (d9 & 255u)], (unsigned)__popcll(m));
            }
        }
        __syncthreads();

        // phase 2a: per-digit exclusive prefix across waves
        if (tid < 256) {
            unsigned run = 0;
            for (int w = 0; w < WAVES; ++w) {
                unsigned t = cnt[w * 256 + tid];
                cnt[w * 256 + tid] = run;
                run += t;
            }
            tot[tid] = run;
        }
        __syncthreads();

        // phase 2b: inclusive scan over tot[256] (Hillis-Steele)
        for (int off = 1; off < 256; off <<= 1) {
            unsigned v = 0;
            if (tid < 256 && tid >= off) v = tot[tid - off];
            __syncthreads();
            if (tid < 256) tot[tid] += v;
            __syncthreads();
        }

        // phase 2c: cnt[w][d] += exclusive digit base
        for (int i = tid; i < WAVES * 256; i += 1024) {
            int d = i & 255;
            unsigned db = (d == 0) ? 0u : tot[d - 1];
            cnt[i] += db;
        }
        __syncthreads();

        // phase 3: re-read + rank + scatter to dst (stable traversal order:
        // wave-major, then iteration j, then lane-minor)
        for (int j = 0; j < 24; ++j) {
            int idx = base_idx + j * 64;
            bool valid = (idx < PP);
            unsigned u = valid ? src[idx] : 0u;
            if (enc) u = (u & 0x80000000u) ? ~u : (u | 0x80000000u);
            unsigned d9 = ((u >> sh) & 255u) | (valid ? 0u : 256u);
            unsigned long long m = matchany9(d9);
            if (valid) {
                int leader = __ffsll(m) - 1;
                unsigned myrank = (unsigned)__popcll(m & lt_mask);
                unsigned old = 0;
                if (lane == leader)
                    old = atomicAdd(&cnt[wbase + (d9 & 255u)], (unsigned)__popcll(m));
                old = __shfl(old, leader, 64);
                dst[old + myrank] = u;
            }
        }
        __syncthreads();
    }

    // after pass 3, rowU holds the fully sorted encoded keys
    const float* wrow = WdOut + (long)k * PP;
    float local = 0.f;
    for (int r = tid; r < PP; r += 1024) {
        unsigned u = rowU[r];
        unsigned raw = (u & 0x80000000u) ? (u & 0x7FFFFFFFu) : ~u;
        local += wrow[r] * __uint_as_float(raw);
    }

#pragma unroll
    for (int off = 32; off > 0; off >>= 1)
        local += __shfl_down(local, off, 64);
    if (lane == 0) red[wave] = local;
    __syncthreads();
    if (tid < WAVES) {
        float x = red[tid];
#pragma unroll
        for (int off = 8; off > 0; off >>= 1)
            x += __shfl_down(x, off, 64);
        if (tid == 0) out[k] = x;
    }
}

// ---------------------------------------------------------------------------
extern "C" void kernel_launch(void* const* d_in, const int* in_sizes, int n_in,
                              void* d_out, int out_size, void* d_ws, size_t ws_size,
                              hipStream_t stream) {
    const float* M      = (const float*)d_in[0];
    const float* Ws_in  = (const float*)d_in[1];
    const float* Wd_in  = (const float*)d_in[2];
    const float* Ws_out = (const float*)d_in[3];
    const float* Wd_out = (const float*)d_in[4];
    float* out = (float*)d_out;

    float* vec  = (float*)d_ws;                    // PP*VLD floats = 18.7 MB
    float* sm2T = vec + (size_t)PP * VLD;          // KK*PP floats  = 17.6 MB
    // k_sort pong buffer overlays vec (dead after k_gemm); KK*PP u32 = 17.6 MB
    unsigned* bufA = (unsigned*)d_ws;

    k_inner<<<PP / 4, 256, 0, stream>>>(M, Ws_in, Wd_in, vec);

    dim3 g2((PP + BP - 1) / BP, (KK + BK - 1) / BK);
    k_gemm<<<g2, 256, 0, stream>>>(vec, Ws_out, sm2T);

    k_sort<<<KK, 1024, 0, stream>>>(sm2T, bufA, Wd_out, out);
}

// Round 7
// 362.514 us; speedup vs baseline: 4.0857x; 1.1843x over previous
//
#include <hip/hip_runtime.h>
#include <hip/hip_bf16.h>

#define DIMK 3
#define NPTS 30
#define KK   181
#define PP   24360
#define DEMB 190
#define VLD  192   // padded vec row stride (floats)

// ---------------------------------------------------------------------------
// Kernel 1: per-permutation inner embed -> vec (PP x VLD)
// ---------------------------------------------------------------------------
__global__ __launch_bounds__(256) void k_inner(
    const float* __restrict__ M,      // 3 x 30
    const float* __restrict__ Ws_in,  // 181 x 3
    const float* __restrict__ Wd_in,  // 181 x 27
    float* __restrict__ vec)          // PP x VLD
{
    __shared__ float Gs[NPTS * NPTS];       // 900
    __shared__ float WsS[KK * 3];           // 543
    __shared__ float WdS[KK * 27];          // 4887

    const int tid = threadIdx.x;

    for (int i = tid; i < KK * 3; i += 256)  WsS[i] = Ws_in[i];
    for (int i = tid; i < KK * 27; i += 256) WdS[i] = Wd_in[i];
    for (int e = tid; e < NPTS * NPTS; e += 256) {
        int a = e / NPTS, b = e % NPTS;
        Gs[e] = M[a] * M[b] + M[NPTS + a] * M[NPTS + b] + M[2 * NPTS + a] * M[2 * NPTS + b];
    }
    __syncthreads();

    const int wave = tid >> 6;
    const int lane = tid & 63;
    const int p = blockIdx.x * 4 + wave;

    // factorial-number-system decode of itertools.permutations(range(30),3)
    int i0 = p / 812;            // 812 = 29*28
    int r  = p - i0 * 812;
    int i1 = r / 28;
    int i2 = r - i1 * 28;
    int c0 = i0;
    int c1 = i1 + (i1 >= c0 ? 1 : 0);
    int lo = min(c0, c1), hi = max(c0, c1);
    int c2 = i2;
    if (c2 >= lo) c2++;
    if (c2 >= hi) c2++;

    float* vrow = vec + (long)p * VLD;

    if (lane < 9) {
        int i = lane / 3, j = lane % 3;
        int ci = (i == 0) ? c0 : ((i == 1) ? c1 : c2);
        int cj = (j == 0) ? c0 : ((j == 1) ? c1 : c2);
        vrow[lane] = Gs[ci * NPTS + cj];
    }

    const float* g0 = Gs + c0 * NPTS;
    const float* g1 = Gs + c1 * NPTS;
    const float* g2 = Gs + c2 * NPTS;
    const float INF = __builtin_inff();

    for (int it = 0; it < 3; ++it) {
        int k = it * 64 + lane;
        if (k < KK) {
            float w0 = WsS[k * 3 + 0], w1 = WsS[k * 3 + 1], w2 = WsS[k * 3 + 2];
            float v[32];
#pragma unroll
            for (int j = 0; j < NPTS; ++j) {
                float val = w0 * g0[j] + w1 * g1[j] + w2 * g2[j];
                bool excl = (j == c0) | (j == c1) | (j == c2);
                v[j] = excl ? INF : val;
            }
            v[30] = INF;
            v[31] = INF;

#pragma unroll
            for (int sz = 2; sz <= 32; sz <<= 1) {
#pragma unroll
                for (int st = sz >> 1; st >= 1; st >>= 1) {
#pragma unroll
                    for (int i = 0; i < 32; ++i) {
                        int j = i ^ st;
                        if (j > i) {
                            bool up = ((i & sz) == 0);
                            float a = v[i], b = v[j];
                            float mn = fminf(a, b), mx = fmaxf(a, b);
                            v[i] = up ? mn : mx;
                            v[j] = up ? mx : mn;
                        }
                    }
                }
            }

            float emb = 0.f;
#pragma unroll
            for (int m = 0; m < 27; ++m) emb += WdS[k * 27 + m] * v[m];
            vrow[9 + k] = emb;
        } else if (k < 183) {
            vrow[9 + k] = 0.f;
        }
    }
}

// ---------------------------------------------------------------------------
// Kernel 2: sm2T[k][p] = dot(vec[p][0:190], Ws_out[k][0:190])
// ---------------------------------------------------------------------------
#define BP  64
#define BK  64
#define DC  96
#define LDT 97

__global__ __launch_bounds__(256) void k_gemm(
    const float* __restrict__ vec,    // PP x VLD
    const float* __restrict__ Wout,   // 181 x 190
    float* __restrict__ sm2T)         // 181 x PP
{
    __shared__ float As[BP * LDT];
    __shared__ float Bs[BK * LDT];

    const int tid = threadIdx.x;
    const int pTile = blockIdx.x * BP;
    const int kTile = blockIdx.y * BK;
    const int tx = tid & 15;
    const int ty = tid >> 4;

    float acc[4][4];
#pragma unroll
    for (int i = 0; i < 4; ++i)
#pragma unroll
        for (int j = 0; j < 4; ++j) acc[i][j] = 0.f;

    for (int ch = 0; ch < 2; ++ch) {
        const int dbase = ch * DC;
        __syncthreads();
        for (int e = tid; e < BP * DC; e += 256) {
            int pl = e / DC, d = e - pl * DC;
            int pg = pTile + pl;
            As[pl * LDT + d] = (pg < PP) ? vec[(long)pg * VLD + dbase + d] : 0.f;
        }
        for (int e = tid; e < BK * DC; e += 256) {
            int kl = e / DC, d = e - kl * DC;
            int kg = kTile + kl;
            int dg = dbase + d;
            Bs[kl * LDT + d] = (kg < KK && dg < DEMB) ? Wout[kg * DEMB + dg] : 0.f;
        }
        __syncthreads();

        for (int d = 0; d < DC; ++d) {
            float a[4], b[4];
#pragma unroll
            for (int i = 0; i < 4; ++i) a[i] = As[(tx + 16 * i) * LDT + d];
#pragma unroll
            for (int j = 0; j < 4; ++j) b[j] = Bs[(ty + 16 * j) * LDT + d];
#pragma unroll
            for (int i = 0; i < 4; ++i)
#pragma unroll
                for (int j = 0; j < 4; ++j) acc[i][j] += a[i] * b[j];
        }
    }

#pragma unroll
    for (int j = 0; j < 4; ++j) {
        int kg = kTile + ty + 16 * j;
        if (kg < KK) {
#pragma unroll
            for (int i = 0; i < 4; ++i) {
                int pg = pTile + tx + 16 * i;
                if (pg < PP) sm2T[(long)kg * PP + pg] = acc[i][j];
            }
        }
    }
}

// ---------------------------------------------------------------------------
// Kernel 3: per-k LSD radix sort (4 x 8-bit), zero per-thread persistent
// state. Round-7: scatter destination alternates global<->LDS
//   pass0: global(sm2T row) -> LDS   pass1: LDS -> global(bufA)
//   pass2: global(bufA)     -> LDS   pass3: LDS -> global(bufA)
// so only 2 of 4 scatters touch global (was 4; 257 MB write-amplified HBM
// traffic in round 6). Phase 1 counting uses plain per-element LDS atomics
// (order-independent; drops 9 ballots/elem). Phase 3 keeps matchany9 ballots
// for stable traversal-order ranks (wave-major, iter, lane-minor).
// LDS: 95 KB keys + 16 KB histograms + 1 KB scan = 112 KB (<160 KB; grid=181
// blocks < 256 CUs so 1 block/CU costs nothing).
// ---------------------------------------------------------------------------
#define WAVES  16
#define WCHUNK 1536             // 64 lanes * 24 iters

__device__ __forceinline__ unsigned long long matchany9(unsigned d) {
    unsigned long long m = ~0ull;
#pragma unroll
    for (int b = 0; b < 9; ++b) {
        unsigned bit = (d >> b) & 1u;
        unsigned long long bal = __ballot(bit);
        m &= bit ? bal : ~bal;
    }
    return m;
}

// one radix pass; SRC_LDS/DST_LDS/ENC are compile-time-constant per call site
#define RADIX_PASS(SH, ENC, SRC_LDS, GSRC, DST_LDS, GDST)                      \
  {                                                                            \
    for (int i = tid; i < WAVES * 256; i += 1024) cnt[i] = 0;                  \
    __syncthreads();                                                           \
    for (int j = 0; j < 24; ++j) {                                             \
      int idx = base_idx + j * 64;                                             \
      bool valid = (idx < PP);                                                 \
      unsigned u = 0u;                                                         \
      if (valid) u = (SRC_LDS) ? keysL[idx] : (GSRC)[idx];                     \
      if (ENC) u = (u & 0x80000000u) ? ~u : (u | 0x80000000u);                 \
      if (valid) atomicAdd(&cnt[wbase + ((u >> (SH)) & 255u)], 1u);            \
    }                                                                          \
    __syncthreads();                                                           \
    if (tid < 256) {                                                           \
      unsigned run = 0;                                                        \
      for (int w = 0; w < WAVES; ++w) {                                        \
        unsigned t = cnt[w * 256 + tid];                                       \
        cnt[w * 256 + tid] = run;                                              \
        run += t;                                                              \
      }                                                                        \
      tot[tid] = run;                                                          \
    }                                                                          \
    __syncthreads();                                                           \
    for (int off = 1; off < 256; off <<= 1) {                                  \
      unsigned v = 0;                                                          \
      if (tid < 256 && tid >= off) v = tot[tid - off];                         \
      __syncthreads();                                                         \
      if (tid < 256) tot[tid] += v;                                            \
      __syncthreads();                                                         \
    }                                                                          \
    for (int i = tid; i < WAVES * 256; i += 1024) {                            \
      int d = i & 255;                                                         \
      unsigned db = (d == 0) ? 0u : tot[d - 1];                                \
      cnt[i] += db;                                                            \
    }                                                                          \
    __syncthreads();                                                           \
    for (int j = 0; j < 24; ++j) {                                             \
      int idx = base_idx + j * 64;                                             \
      bool valid = (idx < PP);                                                 \
      unsigned u = 0u;                                                         \
      if (valid) u = (SRC_LDS) ? keysL[idx] : (GSRC)[idx];                     \
      if (ENC) u = (u & 0x80000000u) ? ~u : (u | 0x80000000u);                 \
      unsigned d9 = ((u >> (SH)) & 255u) | (valid ? 0u : 256u);                \
      unsigned long long mm = matchany9(d9);                                   \
      if (valid) {                                                             \
        int leader = __ffsll(mm) - 1;                                          \
        unsigned myrank = (unsigned)__popcll(mm & lt_mask);                    \
        unsigned old = 0;                                                      \
        if (lane == leader)                                                    \
          old = atomicAdd(&cnt[wbase + (d9 & 255u)], (unsigned)__popcll(mm));  \
        old = (unsigned)__shfl((int)old, leader, 64);                          \
        if (DST_LDS) keysL[old + myrank] = u; else (GDST)[old + myrank] = u;   \
      }                                                                        \
    }                                                                          \
    __syncthreads();                                                           \
  }

__global__ __launch_bounds__(1024) void k_sort(
    float* sm2T,              // 181 x PP (row k read as pass-0 source)
    unsigned* bufA,           // 181 x PP scratch (overlays dead vec)
    const float* __restrict__ WdOut,  // 181 x PP
    float* __restrict__ out)          // 181
{
    __shared__ unsigned keysL[PP];          // 95.2 KiB key buffer
    __shared__ unsigned cnt[WAVES * 256];   // 16 KiB per-wave histograms
    __shared__ unsigned tot[256];
    __shared__ float red[WAVES];

    const int tid  = threadIdx.x;
    const int wave = tid >> 6;
    const int lane = tid & 63;
    const int k    = blockIdx.x;

    const unsigned* rowU = (const unsigned*)sm2T + (long)k * PP;
    unsigned* bA         = bufA + (long)k * PP;

    const int base_idx = wave * WCHUNK + lane;
    const int wbase = wave * 256;
    const unsigned long long lt_mask = (1ull << lane) - 1ull;

    RADIX_PASS(0,  true,  false, rowU, true,  bA)   // G -> LDS (encode)
    RADIX_PASS(8,  false, true,  rowU, false, bA)   // LDS -> G
    RADIX_PASS(16, false, false, bA,   true,  bA)   // G -> LDS
    RADIX_PASS(24, false, true,  rowU, false, bA)   // LDS -> G (final in bufA)

    // bufA row now holds the fully sorted encoded keys (L2-hot)
    const float* wrow = WdOut + (long)k * PP;
    float local = 0.f;
    for (int r = tid; r < PP; r += 1024) {
        unsigned u = bA[r];
        unsigned raw = (u & 0x80000000u) ? (u & 0x7FFFFFFFu) : ~u;
        local += wrow[r] * __uint_as_float(raw);
    }

#pragma unroll
    for (int off = 32; off > 0; off >>= 1)
        local += __shfl_down(local, off, 64);
    if (lane == 0) red[wave] = local;
    __syncthreads();
    if (tid < WAVES) {
        float x = red[tid];
#pragma unroll
        for (int off = 8; off > 0; off >>= 1)
            x += __shfl_down(x, off, 64);
        if (tid == 0) out[k] = x;
    }
}

// ---------------------------------------------------------------------------
extern "C" void kernel_launch(void* const* d_in, const int* in_sizes, int n_in,
                              void* d_out, int out_size, void* d_ws, size_t ws_size,
                              hipStream_t stream) {
    const float* M      = (const float*)d_in[0];
    const float* Ws_in  = (const float*)d_in[1];
    const float* Wd_in  = (const float*)d_in[2];
    const float* Ws_out = (const float*)d_in[3];
    const float* Wd_out = (const float*)d_in[4];
    float* out = (float*)d_out;

    float* vec  = (float*)d_ws;                    // PP*VLD floats = 18.7 MB
    float* sm2T = vec + (size_t)PP * VLD;          // KK*PP floats  = 17.6 MB
    // k_sort scratch overlays vec (dead after k_gemm); KK*PP u32 = 17.6 MB
    unsigned* bufA = (unsigned*)d_ws;

    k_inner<<<PP / 4, 256, 0, stream>>>(M, Ws_in, Wd_in, vec);

    dim3 g2((PP + BP - 1) / BP, (KK + BK - 1) / BK);
    k_gemm<<<g2, 256, 0, stream>>>(vec, Ws_out, sm2T);

    k_sort<<<KK, 1024, 0, stream>>>(sm2T, bufA, Wd_out, out);
}

// Round 8
// 336.853 us; speedup vs baseline: 4.3970x; 1.0762x over previous
//
#include <hip/hip_runtime.h>
#include <hip/hip_bf16.h>

#define DIMK 3
#define NPTS 30
#define KK   181
#define PP   24360
#define DEMB 190
#define VLD  192   // padded vec row stride (floats)

// ---------------------------------------------------------------------------
// Kernel 1: per-permutation inner embed -> vec (PP x VLD)
// One wave per p. The 3 k-chunks (lane, lane+64, lane+128) are processed
// simultaneously: G-row LDS reads shared 3x, three interleaved sort networks
// for ILP. launch_bounds(256,2) caps VGPR at 256 (live set ~125, no spill).
// ---------------------------------------------------------------------------
__global__ __launch_bounds__(256, 2) void k_inner(
    const float* __restrict__ M,      // 3 x 30
    const float* __restrict__ Ws_in,  // 181 x 3
    const float* __restrict__ Wd_in,  // 181 x 27
    float* __restrict__ vec)          // PP x VLD
{
    __shared__ float Gs[NPTS * NPTS];   // 900
    __shared__ float WsS[192 * 3];      // padded to 192 k's
    __shared__ float WdS[192 * 27];

    const int tid = threadIdx.x;

    for (int i = tid; i < 192 * 3; i += 256)  WsS[i] = (i < KK * 3) ? Ws_in[i] : 0.f;
    for (int i = tid; i < 192 * 27; i += 256) WdS[i] = (i < KK * 27) ? Wd_in[i] : 0.f;
    for (int e = tid; e < NPTS * NPTS; e += 256) {
        int a = e / NPTS, b = e % NPTS;
        Gs[e] = M[a] * M[b] + M[NPTS + a] * M[NPTS + b] + M[2 * NPTS + a] * M[2 * NPTS + b];
    }
    __syncthreads();

    const int wave = tid >> 6;
    const int lane = tid & 63;
    const int p = blockIdx.x * 4 + wave;

    // factorial-number-system decode of itertools.permutations(range(30),3)
    int i0 = p / 812;            // 812 = 29*28
    int r  = p - i0 * 812;
    int i1 = r / 28;
    int i2 = r - i1 * 28;
    int c0 = i0;
    int c1 = i1 + (i1 >= c0 ? 1 : 0);
    int lo = min(c0, c1), hi = max(c0, c1);
    int c2 = i2;
    if (c2 >= lo) c2++;
    if (c2 >= hi) c2++;

    float* vrow = vec + (long)p * VLD;

    if (lane < 9) {
        int i = lane / 3, j = lane % 3;
        int ci = (i == 0) ? c0 : ((i == 1) ? c1 : c2);
        int cj = (j == 0) ? c0 : ((j == 1) ? c1 : c2);
        vrow[lane] = Gs[ci * NPTS + cj];
    }

    const float* g0 = Gs + c0 * NPTS;
    const float* g1 = Gs + c1 * NPTS;
    const float* g2 = Gs + c2 * NPTS;
    const float INF = __builtin_inff();

    const int ka = lane, kb = 64 + lane, kc = 128 + lane;
    float wa0 = WsS[ka * 3], wa1 = WsS[ka * 3 + 1], wa2 = WsS[ka * 3 + 2];
    float wb0 = WsS[kb * 3], wb1 = WsS[kb * 3 + 1], wb2 = WsS[kb * 3 + 2];
    float wc0 = WsS[kc * 3], wc1 = WsS[kc * 3 + 1], wc2 = WsS[kc * 3 + 2];

    float va[32], vb[32], vc[32];
#pragma unroll
    for (int j = 0; j < NPTS; ++j) {
        float gj0 = g0[j], gj1 = g1[j], gj2 = g2[j];
        bool excl = (j == c0) | (j == c1) | (j == c2);
        float a = wa0 * gj0 + wa1 * gj1 + wa2 * gj2;
        float b = wb0 * gj0 + wb1 * gj1 + wb2 * gj2;
        float c = wc0 * gj0 + wc1 * gj1 + wc2 * gj2;
        va[j] = excl ? INF : a;
        vb[j] = excl ? INF : b;
        vc[j] = excl ? INF : c;
    }
    va[30] = INF; va[31] = INF;
    vb[30] = INF; vb[31] = INF;
    vc[30] = INF; vc[31] = INF;

    // three interleaved bitonic-32 networks (ascending)
#pragma unroll
    for (int sz = 2; sz <= 32; sz <<= 1) {
#pragma unroll
        for (int st = sz >> 1; st >= 1; st >>= 1) {
#pragma unroll
            for (int i = 0; i < 32; ++i) {
                int j = i ^ st;
                if (j > i) {
                    const bool up = ((i & sz) == 0);
                    float x, y, mn, mx;
                    x = va[i]; y = va[j]; mn = fminf(x, y); mx = fmaxf(x, y);
                    va[i] = up ? mn : mx; va[j] = up ? mx : mn;
                    x = vb[i]; y = vb[j]; mn = fminf(x, y); mx = fmaxf(x, y);
                    vb[i] = up ? mn : mx; vb[j] = up ? mx : mn;
                    x = vc[i]; y = vc[j]; mn = fminf(x, y); mx = fmaxf(x, y);
                    vc[i] = up ? mn : mx; vc[j] = up ? mx : mn;
                }
            }
        }
    }

    float ea = 0.f, eb = 0.f, ec = 0.f;
#pragma unroll
    for (int m = 0; m < 27; ++m) {
        ea += WdS[ka * 27 + m] * va[m];
        eb += WdS[kb * 27 + m] * vb[m];
        ec += WdS[kc * 27 + m] * vc[m];
    }
    vrow[9 + ka] = ea;
    vrow[9 + kb] = eb;
    if (kc < KK)      vrow[9 + kc] = ec;
    else if (kc < 183) vrow[9 + kc] = 0.f;   // pad entries 190,191
}

// ---------------------------------------------------------------------------
// Kernel 2: sm2T[k][p] = dot(vec[p][0:190], Ws_out[k][0:190])
// 128p x 64k tile, d-major LDS (ds_read_b128 fragments), 8x4 micro-tile.
// ---------------------------------------------------------------------------
#define GBP 128
#define GBK 64
#define GDC 48
#define LDA 132   // As row stride (128 + 4, keeps 16B alignment)
#define LDB 68    // Bs row stride (64 + 4)

__global__ __launch_bounds__(256) void k_gemm(
    const float* __restrict__ vec,    // PP x VLD
    const float* __restrict__ Wout,   // 181 x 190
    float* __restrict__ sm2T)         // 181 x PP
{
    __shared__ float As[GDC * LDA];   // [d][pl]
    __shared__ float Bs[GDC * LDB];   // [d][kl]

    const int tid = threadIdx.x;
    const int pTile = blockIdx.x * GBP;
    const int kTile = blockIdx.y * GBK;
    const int tx = tid & 15;   // p dir, 8 p's each
    const int ty = tid >> 4;   // k dir, 4 k's each

    float acc[8][4];
#pragma unroll
    for (int i = 0; i < 8; ++i)
#pragma unroll
        for (int j = 0; j < 4; ++j) acc[i][j] = 0.f;

    for (int ch = 0; ch < 4; ++ch) {
        const int db = ch * GDC;
        __syncthreads();
        // stage A: 128 rows x 48 d (float4 over d, transposed into LDS)
        for (int e = tid; e < GBP * (GDC / 4); e += 256) {   // 1536
            int q = e % 12, pl = e / 12;
            int pg = pTile + pl;
            float4 v = make_float4(0.f, 0.f, 0.f, 0.f);
            if (pg < PP) v = *(const float4*)&vec[(long)pg * VLD + db + q * 4];
            int d0 = q * 4;
            As[(d0 + 0) * LDA + pl] = v.x;
            As[(d0 + 1) * LDA + pl] = v.y;
            As[(d0 + 2) * LDA + pl] = v.z;
            As[(d0 + 3) * LDA + pl] = v.w;
        }
        // stage B: 64 rows x 48 d (scalar; Wout rows are 190 floats, unaligned)
        for (int e = tid; e < GBK * GDC; e += 256) {         // 3072
            int d = e % GDC, kl = e / GDC;
            int kg = kTile + kl, dg = db + d;
            Bs[d * LDB + kl] = (kg < KK && dg < DEMB) ? Wout[kg * DEMB + dg] : 0.f;
        }
        __syncthreads();

        for (int d = 0; d < GDC; ++d) {
            float4 a0 = *(const float4*)&As[d * LDA + tx * 8];
            float4 a1 = *(const float4*)&As[d * LDA + tx * 8 + 4];
            float4 b0 = *(const float4*)&Bs[d * LDB + ty * 4];
            float a[8] = {a0.x, a0.y, a0.z, a0.w, a1.x, a1.y, a1.z, a1.w};
            float b[4] = {b0.x, b0.y, b0.z, b0.w};
#pragma unroll
            for (int i = 0; i < 8; ++i)
#pragma unroll
                for (int j = 0; j < 4; ++j) acc[i][j] += a[i] * b[j];
        }
    }

#pragma unroll
    for (int j = 0; j < 4; ++j) {
        int kg = kTile + ty * 4 + j;
        if (kg < KK) {
            int pg0 = pTile + tx * 8;
            if (pg0 < PP) {   // PP % 8 == 0: float4 pairs fully valid or fully out
                float4 s0 = {acc[0][j], acc[1][j], acc[2][j], acc[3][j]};
                float4 s1 = {acc[4][j], acc[5][j], acc[6][j], acc[7][j]};
                *(float4*)&sm2T[(long)kg * PP + pg0]     = s0;
                *(float4*)&sm2T[(long)kg * PP + pg0 + 4] = s1;
            }
        }
    }
}

// ---------------------------------------------------------------------------
// Kernel 3: per-k LSD radix sort (4 x 8-bit), zero per-thread persistent
// state. Round-8: (a) next-pass histogram fused into each scatter (dest ->
// dest wave known), killing the 3 standalone count traversals; (b) final dot
// fused into pass-3 (local += Wd[dest]*val), killing the last global write
// and re-read; (c) 3-barrier wave-shuffle scan replaces 16-barrier
// Hillis-Steele. Element traversals: 8 -> 5.
// ---------------------------------------------------------------------------
#define WAVES  16
#define WCHUNK 1536             // 64 lanes * 24 iters

__device__ __forceinline__ unsigned long long matchany9(unsigned d) {
    unsigned long long m = ~0ull;
#pragma unroll
    for (int b = 0; b < 9; ++b) {
        unsigned bit = (d >> b) & 1u;
        unsigned long long bal = __ballot(bit);
        m &= bit ? bal : ~bal;
    }
    return m;
}

// counts in cntC -> stable scatter offsets in cntC; cntZ (if non-null) zeroed.
__device__ __forceinline__ void scan_hist(unsigned* cntC, unsigned* cntZ,
                                          unsigned* tot, int tid) {
    if (tid < 256) {            // exclusive prefix across waves, per digit
        unsigned run = 0;
        for (int w = 0; w < WAVES; ++w) {
            unsigned t = cntC[w * 256 + tid];
            cntC[w * 256 + tid] = run;
            run += t;
        }
        tot[tid] = run;
    }
    __syncthreads();
    if (tid < 64) {             // inclusive scan of tot[256], 4 bins/lane
        unsigned t0 = tot[tid * 4], t1 = tot[tid * 4 + 1];
        unsigned t2 = tot[tid * 4 + 2], t3 = tot[tid * 4 + 3];
        unsigned s = t0 + t1 + t2 + t3;
        unsigned sc = s;
#pragma unroll
        for (int off = 1; off < 64; off <<= 1) {
            unsigned o = (unsigned)__shfl_up((int)sc, off, 64);
            if (tid >= off) sc += o;
        }
        unsigned ex = sc - s;
        tot[tid * 4]     = ex + t0;
        tot[tid * 4 + 1] = ex + t0 + t1;
        tot[tid * 4 + 2] = ex + t0 + t1 + t2;
        tot[tid * 4 + 3] = ex + s;
    } else if (cntZ) {
        for (int i = tid - 64; i < WAVES * 256; i += 1024 - 64) cntZ[i] = 0;
    }
    __syncthreads();
    for (int i = tid; i < WAVES * 256; i += 1024) {
        int d = i & 255;
        unsigned db = (d == 0) ? 0u : tot[d - 1];
        cntC[i] += db;
    }
    __syncthreads();
}

__global__ __launch_bounds__(1024) void k_sort(
    float* sm2T,              // 181 x PP (row k read as pass-0 source)
    unsigned* bufA,           // 181 x PP scratch (overlays dead vec)
    const float* __restrict__ WdOut,  // 181 x PP
    float* __restrict__ out)          // 181
{
    __shared__ unsigned keysL[PP];          // 95.2 KiB
    __shared__ unsigned cntA[WAVES * 256];  // 16 KiB
    __shared__ unsigned cntB[WAVES * 256];  // 16 KiB
    __shared__ unsigned tot[256];
    __shared__ float red[WAVES];

    const int tid  = threadIdx.x;
    const int wave = tid >> 6;
    const int lane = tid & 63;
    const int k    = blockIdx.x;

    const unsigned* rowU = (const unsigned*)sm2T + (long)k * PP;
    unsigned* bA         = bufA + (long)k * PP;
    const float* wrow    = WdOut + (long)k * PP;

    const int base_idx = wave * WCHUNK + lane;
    const int wbase = wave * 256;
    const unsigned long long lt_mask = (1ull << lane) - 1ull;

// scatter pass: compute dest; optionally write LDS/global; optionally count
// next digit into CNTN; optionally accumulate the final dot.
#define SCATTER(SH, ENC, SRC_LDS, GSRC, DST_LDS, GDST, CNT, DO_NEXT, NSH, CNTN, DO_DOT) \
  for (int j = 0; j < 24; ++j) {                                               \
    int idx = base_idx + j * 64;                                               \
    bool valid = (idx < PP);                                                   \
    unsigned u = 0u;                                                           \
    if (valid) u = (SRC_LDS) ? keysL[idx] : (GSRC)[idx];                       \
    if (ENC) u = (u & 0x80000000u) ? ~u : (u | 0x80000000u);                   \
    unsigned d9 = ((u >> (SH)) & 255u) | (valid ? 0u : 256u);                  \
    unsigned long long mm = matchany9(d9);                                     \
    if (valid) {                                                               \
      int leader = __ffsll(mm) - 1;                                            \
      unsigned myrank = (unsigned)__popcll(mm & lt_mask);                      \
      unsigned old = 0;                                                        \
      if (lane == leader)                                                      \
        old = atomicAdd(&(CNT)[wbase + (d9 & 255u)], (unsigned)__popcll(mm));  \
      old = (unsigned)__shfl((int)old, leader, 64);                            \
      unsigned dest = old + myrank;                                            \
      if (DO_DOT) {                                                            \
        unsigned raw = (u & 0x80000000u) ? (u & 0x7FFFFFFFu) : ~u;             \
        local += wrow[dest] * __uint_as_float(raw);                            \
      } else {                                                                 \
        if (DST_LDS) keysL[dest] = u; else (GDST)[dest] = u;                   \
      }                                                                        \
      if (DO_NEXT) {                                                           \
        unsigned nd = (u >> (NSH)) & 255u;                                     \
        unsigned dw = dest / WCHUNK;                                           \
        atomicAdd(&(CNTN)[dw * 256 + nd], 1u);                                 \
      }                                                                        \
    }                                                                          \
  }                                                                            \
  __syncthreads();

    float local = 0.f;

    // pass 0 count (standalone)
    for (int i = tid; i < WAVES * 256; i += 1024) cntA[i] = 0;
    __syncthreads();
    for (int j = 0; j < 24; ++j) {
        int idx = base_idx + j * 64;
        if (idx < PP) {
            unsigned u = rowU[idx];
            u = (u & 0x80000000u) ? ~u : (u | 0x80000000u);
            atomicAdd(&cntA[wbase + (u & 255u)], 1u);
        }
    }
    __syncthreads();

    scan_hist(cntA, cntB, tot, tid);
    SCATTER(0,  true,  false, rowU, true,  bA, cntA, true,  8,  cntB, false)  // G->LDS
    scan_hist(cntB, cntA, tot, tid);
    SCATTER(8,  false, true,  rowU, false, bA, cntB, true,  16, cntA, false)  // LDS->G
    scan_hist(cntA, cntB, tot, tid);
    SCATTER(16, false, false, bA,   true,  bA, cntA, true,  24, cntB, false)  // G->LDS
    scan_hist(cntB, (unsigned*)0, tot, tid);
    SCATTER(24, false, true,  rowU, false, bA, cntB, false, 0,  cntA, true)   // LDS->dot
#undef SCATTER

    // block reduction of local
#pragma unroll
    for (int off = 32; off > 0; off >>= 1)
        local += __shfl_down(local, off, 64);
    if (lane == 0) red[wave] = local;
    __syncthreads();
    if (tid < WAVES) {
        float x = red[tid];
#pragma unroll
        for (int off = 8; off > 0; off >>= 1)
            x += __shfl_down(x, off, 64);
        if (tid == 0) out[k] = x;
    }
}

// ---------------------------------------------------------------------------
extern "C" void kernel_launch(void* const* d_in, const int* in_sizes, int n_in,
                              void* d_out, int out_size, void* d_ws, size_t ws_size,
                              hipStream_t stream) {
    const float* M      = (const float*)d_in[0];
    const float* Ws_in  = (const float*)d_in[1];
    const float* Wd_in  = (const float*)d_in[2];
    const float* Ws_out = (const float*)d_in[3];
    const float* Wd_out = (const float*)d_in[4];
    float* out = (float*)d_out;

    float* vec  = (float*)d_ws;                    // PP*VLD floats = 18.7 MB
    float* sm2T = vec + (size_t)PP * VLD;          // KK*PP floats  = 17.6 MB
    // k_sort scratch overlays vec (dead after k_gemm)
    unsigned* bufA = (unsigned*)d_ws;

    k_inner<<<PP / 4, 256, 0, stream>>>(M, Ws_in, Wd_in, vec);

    dim3 g2((PP + GBP - 1) / GBP, (KK + GBK - 1) / GBK);
    k_gemm<<<g2, 256, 0, stream>>>(vec, Ws_out, sm2T);

    k_sort<<<KK, 1024, 0, stream>>>(sm2T, bufA, Wd_out, out);
}

// Round 9
// 324.314 us; speedup vs baseline: 4.5670x; 1.0387x over previous
//
#include <hip/hip_runtime.h>
#include <hip/hip_bf16.h>

#define DIMK 3
#define NPTS 30
#define KK   181
#define PP   24360
#define DEMB 190
#define VLD  192   // padded vec row stride (floats)

// ---------------------------------------------------------------------------
// Kernel 1: per-permutation inner embed -> vec (PP x VLD)
// Round-9: one sort network per LANE (wave g -> p=g/3, chunk=g%3; lane k =
// chunk*64+lane). Live set ~55 VGPR -> 4 waves/SIMD (round-8 had 3 networks/
// lane: 96 floats -> AGPR parking, 21% occupancy). Batcher odd-even merge
// (191 CEs) instead of bitonic (240). Gs/WsS/WdS are p-independent so a
// block may span two p's.
// ---------------------------------------------------------------------------
__global__ __launch_bounds__(256, 4) void k_inner(
    const float* __restrict__ M,      // 3 x 30
    const float* __restrict__ Ws_in,  // 181 x 3
    const float* __restrict__ Wd_in,  // 181 x 27
    float* __restrict__ vec)          // PP x VLD
{
    __shared__ float Gs[NPTS * NPTS];   // 900
    __shared__ float WsS[192 * 3];      // zero-padded to 192 k's
    __shared__ float WdS[192 * 27];

    const int tid = threadIdx.x;

    for (int i = tid; i < 192 * 3; i += 256)  WsS[i] = (i < KK * 3) ? Ws_in[i] : 0.f;
    for (int i = tid; i < 192 * 27; i += 256) WdS[i] = (i < KK * 27) ? Wd_in[i] : 0.f;
    for (int e = tid; e < NPTS * NPTS; e += 256) {
        int a = e / NPTS, b = e % NPTS;
        Gs[e] = M[a] * M[b] + M[NPTS + a] * M[NPTS + b] + M[2 * NPTS + a] * M[2 * NPTS + b];
    }
    __syncthreads();

    const int wave = tid >> 6;
    const int lane = tid & 63;
    const int g = blockIdx.x * 4 + wave;      // 0 .. PP*3-1 (grid exact)
    const int p = g / 3;
    const int chunk = g - 3 * p;

    // factorial-number-system decode of itertools.permutations(range(30),3)
    int i0 = p / 812;            // 812 = 29*28
    int r  = p - i0 * 812;
    int i1 = r / 28;
    int i2 = r - i1 * 28;
    int c0 = i0;
    int c1 = i1 + (i1 >= c0 ? 1 : 0);
    int lo = min(c0, c1), hi = max(c0, c1);
    int c2 = i2;
    if (c2 >= lo) c2++;
    if (c2 >= hi) c2++;

    float* vrow = vec + (long)p * VLD;

    if (chunk == 0 && lane < 9) {
        int i = lane / 3, j = lane % 3;
        int ci = (i == 0) ? c0 : ((i == 1) ? c1 : c2);
        int cj = (j == 0) ? c0 : ((j == 1) ? c1 : c2);
        vrow[lane] = Gs[ci * NPTS + cj];
    }

    const float* g0 = Gs + c0 * NPTS;
    const float* g1 = Gs + c1 * NPTS;
    const float* g2 = Gs + c2 * NPTS;
    const float INF = __builtin_inff();

    const int k = chunk * 64 + lane;          // 0..191 (WsS/WdS padded)
    const float w0 = WsS[k * 3 + 0], w1 = WsS[k * 3 + 1], w2 = WsS[k * 3 + 2];

    float v[32];
#pragma unroll
    for (int j = 0; j < NPTS; ++j) {
        float val = w0 * g0[j] + w1 * g1[j] + w2 * g2[j];
        bool excl = (j == c0) | (j == c1) | (j == c2);
        v[j] = excl ? INF : val;
    }
    v[30] = INF;
    v[31] = INF;

    // Batcher odd-even mergesort, n=32, ascending (191 compare-exchanges)
#pragma unroll
    for (int pw = 1; pw < 32; pw <<= 1) {
#pragma unroll
        for (int kk = pw; kk >= 1; kk >>= 1) {
#pragma unroll
            for (int j = kk % pw; j + kk < 32; j += 2 * kk) {
#pragma unroll
                for (int i = 0; i < kk; ++i) {
                    int a = i + j, b = i + j + kk;
                    if (a / (pw * 2) == b / (pw * 2)) {
                        float x = v[a], y = v[b];
                        v[a] = fminf(x, y);
                        v[b] = fmaxf(x, y);
                    }
                }
            }
        }
    }

    float emb = 0.f;
#pragma unroll
    for (int m = 0; m < 27; ++m) emb += WdS[k * 27 + m] * v[m];

    if (k < KK)       vrow[9 + k] = emb;
    else if (k < 183) vrow[9 + k] = 0.f;   // pad entries 190,191 (k_gemm reads them)
}

// ---------------------------------------------------------------------------
// Kernel 2: sm2T[k][p] = dot(vec[p][0:190], Ws_out[k][0:190])
// 128p x 64k tile, d-major LDS (ds_read_b128 fragments), 8x4 micro-tile.
// ---------------------------------------------------------------------------
#define GBP 128
#define GBK 64
#define GDC 48
#define LDA 132   // As row stride (128 + 4, keeps 16B alignment)
#define LDB 68    // Bs row stride (64 + 4)

__global__ __launch_bounds__(256) void k_gemm(
    const float* __restrict__ vec,    // PP x VLD
    const float* __restrict__ Wout,   // 181 x 190
    float* __restrict__ sm2T)         // 181 x PP
{
    __shared__ float As[GDC * LDA];   // [d][pl]
    __shared__ float Bs[GDC * LDB];   // [d][kl]

    const int tid = threadIdx.x;
    const int pTile = blockIdx.x * GBP;
    const int kTile = blockIdx.y * GBK;
    const int tx = tid & 15;   // p dir, 8 p's each
    const int ty = tid >> 4;   // k dir, 4 k's each

    float acc[8][4];
#pragma unroll
    for (int i = 0; i < 8; ++i)
#pragma unroll
        for (int j = 0; j < 4; ++j) acc[i][j] = 0.f;

    for (int ch = 0; ch < 4; ++ch) {
        const int db = ch * GDC;
        __syncthreads();
        // stage A: 128 rows x 48 d (float4 over d, transposed into LDS)
        for (int e = tid; e < GBP * (GDC / 4); e += 256) {   // 1536
            int q = e % 12, pl = e / 12;
            int pg = pTile + pl;
            float4 v = make_float4(0.f, 0.f, 0.f, 0.f);
            if (pg < PP) v = *(const float4*)&vec[(long)pg * VLD + db + q * 4];
            int d0 = q * 4;
            As[(d0 + 0) * LDA + pl] = v.x;
            As[(d0 + 1) * LDA + pl] = v.y;
            As[(d0 + 2) * LDA + pl] = v.z;
            As[(d0 + 3) * LDA + pl] = v.w;
        }
        // stage B: 64 rows x 48 d (scalar; Wout rows are 190 floats, unaligned)
        for (int e = tid; e < GBK * GDC; e += 256) {         // 3072
            int d = e % GDC, kl = e / GDC;
            int kg = kTile + kl, dg = db + d;
            Bs[d * LDB + kl] = (kg < KK && dg < DEMB) ? Wout[kg * DEMB + dg] : 0.f;
        }
        __syncthreads();

        for (int d = 0; d < GDC; ++d) {
            float4 a0 = *(const float4*)&As[d * LDA + tx * 8];
            float4 a1 = *(const float4*)&As[d * LDA + tx * 8 + 4];
            float4 b0 = *(const float4*)&Bs[d * LDB + ty * 4];
            float a[8] = {a0.x, a0.y, a0.z, a0.w, a1.x, a1.y, a1.z, a1.w};
            float b[4] = {b0.x, b0.y, b0.z, b0.w};
#pragma unroll
            for (int i = 0; i < 8; ++i)
#pragma unroll
                for (int j = 0; j < 4; ++j) acc[i][j] += a[i] * b[j];
        }
    }

#pragma unroll
    for (int j = 0; j < 4; ++j) {
        int kg = kTile + ty * 4 + j;
        if (kg < KK) {
            int pg0 = pTile + tx * 8;
            if (pg0 < PP) {   // PP % 8 == 0: float4 pairs fully valid or fully out
                float4 s0 = {acc[0][j], acc[1][j], acc[2][j], acc[3][j]};
                float4 s1 = {acc[4][j], acc[5][j], acc[6][j], acc[7][j]};
                *(float4*)&sm2T[(long)kg * PP + pg0]     = s0;
                *(float4*)&sm2T[(long)kg * PP + pg0 + 4] = s1;
            }
        }
    }
}

// ---------------------------------------------------------------------------
// Kernel 3: per-k LSD radix sort (4 x 8-bit), zero per-thread persistent
// state; fused next-pass histograms, fused final dot, wave-shuffle scan.
// ---------------------------------------------------------------------------
#define WAVES  16
#define WCHUNK 1536             // 64 lanes * 24 iters

__device__ __forceinline__ unsigned long long matchany9(unsigned d) {
    unsigned long long m = ~0ull;
#pragma unroll
    for (int b = 0; b < 9; ++b) {
        unsigned bit = (d >> b) & 1u;
        unsigned long long bal = __ballot(bit);
        m &= bit ? bal : ~bal;
    }
    return m;
}

// counts in cntC -> stable scatter offsets in cntC; cntZ (if non-null) zeroed.
__device__ __forceinline__ void scan_hist(unsigned* cntC, unsigned* cntZ,
                                          unsigned* tot, int tid) {
    if (tid < 256) {            // exclusive prefix across waves, per digit
        unsigned run = 0;
        for (int w = 0; w < WAVES; ++w) {
            unsigned t = cntC[w * 256 + tid];
            cntC[w * 256 + tid] = run;
            run += t;
        }
        tot[tid] = run;
    }
    __syncthreads();
    if (tid < 64) {             // inclusive scan of tot[256], 4 bins/lane
        unsigned t0 = tot[tid * 4], t1 = tot[tid * 4 + 1];
        unsigned t2 = tot[tid * 4 + 2], t3 = tot[tid * 4 + 3];
        unsigned s = t0 + t1 + t2 + t3;
        unsigned sc = s;
#pragma unroll
        for (int off = 1; off < 64; off <<= 1) {
            unsigned o = (unsigned)__shfl_up((int)sc, off, 64);
            if (tid >= off) sc += o;
        }
        unsigned ex = sc - s;
        tot[tid * 4]     = ex + t0;
        tot[tid * 4 + 1] = ex + t0 + t1;
        tot[tid * 4 + 2] = ex + t0 + t1 + t2;
        tot[tid * 4 + 3] = ex + s;
    } else if (cntZ) {
        for (int i = tid - 64; i < WAVES * 256; i += 1024 - 64) cntZ[i] = 0;
    }
    __syncthreads();
    for (int i = tid; i < WAVES * 256; i += 1024) {
        int d = i & 255;
        unsigned db = (d == 0) ? 0u : tot[d - 1];
        cntC[i] += db;
    }
    __syncthreads();
}

__global__ __launch_bounds__(1024) void k_sort(
    float* sm2T,              // 181 x PP (row k read as pass-0 source)
    unsigned* bufA,           // 181 x PP scratch (overlays dead vec)
    const float* __restrict__ WdOut,  // 181 x PP
    float* __restrict__ out)          // 181
{
    __shared__ unsigned keysL[PP];          // 95.2 KiB
    __shared__ unsigned cntA[WAVES * 256];  // 16 KiB
    __shared__ unsigned cntB[WAVES * 256];  // 16 KiB
    __shared__ unsigned tot[256];
    __shared__ float red[WAVES];

    const int tid  = threadIdx.x;
    const int wave = tid >> 6;
    const int lane = tid & 63;
    const int k    = blockIdx.x;

    const unsigned* rowU = (const unsigned*)sm2T + (long)k * PP;
    unsigned* bA         = bufA + (long)k * PP;
    const float* wrow    = WdOut + (long)k * PP;

    const int base_idx = wave * WCHUNK + lane;
    const int wbase = wave * 256;
    const unsigned long long lt_mask = (1ull << lane) - 1ull;

// scatter pass: compute dest; optionally write LDS/global; optionally count
// next digit into CNTN; optionally accumulate the final dot.
#define SCATTER(SH, ENC, SRC_LDS, GSRC, DST_LDS, GDST, CNT, DO_NEXT, NSH, CNTN, DO_DOT) \
  for (int j = 0; j < 24; ++j) {                                               \
    int idx = base_idx + j * 64;                                               \
    bool valid = (idx < PP);                                                   \
    unsigned u = 0u;                                                           \
    if (valid) u = (SRC_LDS) ? keysL[idx] : (GSRC)[idx];                       \
    if (ENC) u = (u & 0x80000000u) ? ~u : (u | 0x80000000u);                   \
    unsigned d9 = ((u >> (SH)) & 255u) | (valid ? 0u : 256u);                  \
    unsigned long long mm = matchany9(d9);                                     \
    if (valid) {                                                               \
      int leader = __ffsll(mm) - 1;                                            \
      unsigned myrank = (unsigned)__popcll(mm & lt_mask);                      \
      unsigned old = 0;                                                        \
      if (lane == leader)                                                      \
        old = atomicAdd(&(CNT)[wbase + (d9 & 255u)], (unsigned)__popcll(mm));  \
      old = (unsigned)__shfl((int)old, leader, 64);                            \
      unsigned dest = old + myrank;                                            \
      if (DO_DOT) {                                                            \
        unsigned raw = (u & 0x80000000u) ? (u & 0x7FFFFFFFu) : ~u;             \
        local += wrow[dest] * __uint_as_float(raw);                            \
      } else {                                                                 \
        if (DST_LDS) keysL[dest] = u; else (GDST)[dest] = u;                   \
      }                                                                        \
      if (DO_NEXT) {                                                           \
        unsigned nd = (u >> (NSH)) & 255u;                                     \
        unsigned dw = dest / WCHUNK;                                           \
        atomicAdd(&(CNTN)[dw * 256 + nd], 1u);                                 \
      }                                                                        \
    }                                                                          \
  }                                                                            \
  __syncthreads();

    float local = 0.f;

    // pass 0 count (standalone)
    for (int i = tid; i < WAVES * 256; i += 1024) cntA[i] = 0;
    __syncthreads();
    for (int j = 0; j < 24; ++j) {
        int idx = base_idx + j * 64;
        if (idx < PP) {
            unsigned u = rowU[idx];
            u = (u & 0x80000000u) ? ~u : (u | 0x80000000u);
            atomicAdd(&cntA[wbase + (u & 255u)], 1u);
        }
    }
    __syncthreads();

    scan_hist(cntA, cntB, tot, tid);
    SCATTER(0,  true,  false, rowU, true,  bA, cntA, true,  8,  cntB, false)  // G->LDS
    scan_hist(cntB, cntA, tot, tid);
    SCATTER(8,  false, true,  rowU, false, bA, cntB, true,  16, cntA, false)  // LDS->G
    scan_hist(cntA, cntB, tot, tid);
    SCATTER(16, false, false, bA,   true,  bA, cntA, true,  24, cntB, false)  // G->LDS
    scan_hist(cntB, (unsigned*)0, tot, tid);
    SCATTER(24, false, true,  rowU, false, bA, cntB, false, 0,  cntA, true)   // LDS->dot
#undef SCATTER

    // block reduction of local
#pragma unroll
    for (int off = 32; off > 0; off >>= 1)
        local += __shfl_down(local, off, 64);
    if (lane == 0) red[wave] = local;
    __syncthreads();
    if (tid < WAVES) {
        float x = red[tid];
#pragma unroll
        for (int off = 8; off > 0; off >>= 1)
            x += __shfl_down(x, off, 64);
        if (tid == 0) out[k] = x;
    }
}

// ---------------------------------------------------------------------------
extern "C" void kernel_launch(void* const* d_in, const int* in_sizes, int n_in,
                              void* d_out, int out_size, void* d_ws, size_t ws_size,
                              hipStream_t stream) {
    const float* M      = (const float*)d_in[0];
    const float* Ws_in  = (const float*)d_in[1];
    const float* Wd_in  = (const float*)d_in[2];
    const float* Ws_out = (const float*)d_in[3];
    const float* Wd_out = (const float*)d_in[4];
    float* out = (float*)d_out;

    float* vec  = (float*)d_ws;                    // PP*VLD floats = 18.7 MB
    float* sm2T = vec + (size_t)PP * VLD;          // KK*PP floats  = 17.6 MB
    // k_sort scratch overlays vec (dead after k_gemm)
    unsigned* bufA = (unsigned*)d_ws;

    k_inner<<<(PP * 3) / 4, 256, 0, stream>>>(M, Ws_in, Wd_in, vec);

    dim3 g2((PP + GBP - 1) / GBP, (KK + GBK - 1) / GBK);
    k_gemm<<<g2, 256, 0, stream>>>(vec, Ws_out, sm2T);

    k_sort<<<KK, 1024, 0, stream>>>(sm2T, bufA, Wd_out, out);
}

// Round 10
// 303.775 us; speedup vs baseline: 4.8758x; 1.0676x over previous
//
#include <hip/hip_runtime.h>
#include <hip/hip_bf16.h>

#define DIMK 3
#define NPTS 30
#define KK   181
#define PP   24360
#define DEMB 190
#define VLD  192   // padded vec row stride (floats)

// ---------------------------------------------------------------------------
// Kernel 1: per-permutation inner embed -> vec (PP x VLD)
// Round-10: persistent waves. grid=1536 blocks x 4 waves = 6144 waves; wave
// wid owns chunk=wid%3 (k = chunk*64+lane fixed) and strides p by 2048
// (~12 tasks/wave). Block staging (Gs/WsS/WdS, 25.4 KB) runs once per block
// (was once per 4 tasks across 18270 blocks). launch_bounds(256,6): 6 blocks
// /CU (LDS 6x25.4=152<160 KB) -> 24 waves/CU, VGPR cap 102 >> ~45 live.
// ---------------------------------------------------------------------------
#define NSTREAM 2048   // 6144 waves / 3 chunks

__global__ __launch_bounds__(256, 6) void k_inner(
    const float* __restrict__ M,      // 3 x 30
    const float* __restrict__ Ws_in,  // 181 x 3
    const float* __restrict__ Wd_in,  // 181 x 27
    float* __restrict__ vec)          // PP x VLD
{
    __shared__ float Gs[NPTS * NPTS];   // 3.6 KB
    __shared__ float WsS[KK * 3];       // 2.2 KB
    __shared__ float WdS[KK * 27];      // 19.5 KB

    const int tid = threadIdx.x;

    for (int i = tid; i < KK * 3; i += 256)  WsS[i] = Ws_in[i];
    for (int i = tid; i < KK * 27; i += 256) WdS[i] = Wd_in[i];
    for (int e = tid; e < NPTS * NPTS; e += 256) {
        int a = e / NPTS, b = e % NPTS;
        Gs[e] = M[a] * M[b] + M[NPTS + a] * M[NPTS + b] + M[2 * NPTS + a] * M[2 * NPTS + b];
    }
    __syncthreads();

    const int wave = tid >> 6;
    const int lane = tid & 63;
    const int wid = blockIdx.x * 4 + wave;    // 0..6143
    const int chunk = wid % 3;
    const int pstream = wid / 3;              // 0..2047
    const int k = chunk * 64 + lane;          // 0..191

    const float INF = __builtin_inff();
    const bool kvalid = (k < KK);
    const float w0 = kvalid ? WsS[k * 3 + 0] : 0.f;
    const float w1 = kvalid ? WsS[k * 3 + 1] : 0.f;
    const float w2 = kvalid ? WsS[k * 3 + 2] : 0.f;

    for (int p = pstream; p < PP; p += NSTREAM) {
        // factorial-number-system decode of itertools.permutations(range(30),3)
        int i0 = p / 812;            // 812 = 29*28
        int r  = p - i0 * 812;
        int i1 = r / 28;
        int i2 = r - i1 * 28;
        int c0 = i0;
        int c1 = i1 + (i1 >= c0 ? 1 : 0);
        int lo = min(c0, c1), hi = max(c0, c1);
        int c2 = i2;
        if (c2 >= lo) c2++;
        if (c2 >= hi) c2++;

        float* vrow = vec + (long)p * VLD;

        if (chunk == 0 && lane < 9) {
            int i = lane / 3, j = lane % 3;
            int ci = (i == 0) ? c0 : ((i == 1) ? c1 : c2);
            int cj = (j == 0) ? c0 : ((j == 1) ? c1 : c2);
            vrow[lane] = Gs[ci * NPTS + cj];
        }

        const float* g0 = Gs + c0 * NPTS;
        const float* g1 = Gs + c1 * NPTS;
        const float* g2 = Gs + c2 * NPTS;

        float v[32];
#pragma unroll
        for (int j = 0; j < NPTS; ++j) {
            float val = w0 * g0[j] + w1 * g1[j] + w2 * g2[j];
            bool excl = (j == c0) | (j == c1) | (j == c2);
            v[j] = excl ? INF : val;
        }
        v[30] = INF;
        v[31] = INF;

        // Batcher odd-even mergesort, n=32, ascending (191 compare-exchanges)
#pragma unroll
        for (int pw = 1; pw < 32; pw <<= 1) {
#pragma unroll
            for (int kk = pw; kk >= 1; kk >>= 1) {
#pragma unroll
                for (int j = kk % pw; j + kk < 32; j += 2 * kk) {
#pragma unroll
                    for (int i = 0; i < kk; ++i) {
                        int a = i + j, b = i + j + kk;
                        if (a / (pw * 2) == b / (pw * 2)) {
                            float x = v[a], y = v[b];
                            v[a] = fminf(x, y);
                            v[b] = fmaxf(x, y);
                        }
                    }
                }
            }
        }

        float emb = 0.f;
        if (kvalid) {
#pragma unroll
            for (int m = 0; m < 27; ++m) emb += WdS[k * 27 + m] * v[m];
            vrow[9 + k] = emb;
        } else if (k < 183) {
            vrow[9 + k] = 0.f;   // pad entries 190,191 (k_gemm reads them)
        }
    }
}

// ---------------------------------------------------------------------------
// Kernel 2: sm2T[k][p] = dot(vec[p][0:190], Ws_out[k][0:190])
// 128p x 64k tile, d-major LDS (ds_read_b128 fragments), 8x4 micro-tile.
// ---------------------------------------------------------------------------
#define GBP 128
#define GBK 64
#define GDC 48
#define LDA 132   // As row stride (128 + 4, keeps 16B alignment)
#define LDB 68    // Bs row stride (64 + 4)

__global__ __launch_bounds__(256) void k_gemm(
    const float* __restrict__ vec,    // PP x VLD
    const float* __restrict__ Wout,   // 181 x 190
    float* __restrict__ sm2T)         // 181 x PP
{
    __shared__ float As[GDC * LDA];   // [d][pl]
    __shared__ float Bs[GDC * LDB];   // [d][kl]

    const int tid = threadIdx.x;
    const int pTile = blockIdx.x * GBP;
    const int kTile = blockIdx.y * GBK;
    const int tx = tid & 15;   // p dir, 8 p's each
    const int ty = tid >> 4;   // k dir, 4 k's each

    float acc[8][4];
#pragma unroll
    for (int i = 0; i < 8; ++i)
#pragma unroll
        for (int j = 0; j < 4; ++j) acc[i][j] = 0.f;

    for (int ch = 0; ch < 4; ++ch) {
        const int db = ch * GDC;
        __syncthreads();
        // stage A: 128 rows x 48 d (float4 over d, transposed into LDS)
        for (int e = tid; e < GBP * (GDC / 4); e += 256) {   // 1536
            int q = e % 12, pl = e / 12;
            int pg = pTile + pl;
            float4 v = make_float4(0.f, 0.f, 0.f, 0.f);
            if (pg < PP) v = *(const float4*)&vec[(long)pg * VLD + db + q * 4];
            int d0 = q * 4;
            As[(d0 + 0) * LDA + pl] = v.x;
            As[(d0 + 1) * LDA + pl] = v.y;
            As[(d0 + 2) * LDA + pl] = v.z;
            As[(d0 + 3) * LDA + pl] = v.w;
        }
        // stage B: 64 rows x 48 d (scalar; Wout rows are 190 floats, unaligned)
        for (int e = tid; e < GBK * GDC; e += 256) {         // 3072
            int d = e % GDC, kl = e / GDC;
            int kg = kTile + kl, dg = db + d;
            Bs[d * LDB + kl] = (kg < KK && dg < DEMB) ? Wout[kg * DEMB + dg] : 0.f;
        }
        __syncthreads();

        for (int d = 0; d < GDC; ++d) {
            float4 a0 = *(const float4*)&As[d * LDA + tx * 8];
            float4 a1 = *(const float4*)&As[d * LDA + tx * 8 + 4];
            float4 b0 = *(const float4*)&Bs[d * LDB + ty * 4];
            float a[8] = {a0.x, a0.y, a0.z, a0.w, a1.x, a1.y, a1.z, a1.w};
            float b[4] = {b0.x, b0.y, b0.z, b0.w};
#pragma unroll
            for (int i = 0; i < 8; ++i)
#pragma unroll
                for (int j = 0; j < 4; ++j) acc[i][j] += a[i] * b[j];
        }
    }

#pragma unroll
    for (int j = 0; j < 4; ++j) {
        int kg = kTile + ty * 4 + j;
        if (kg < KK) {
            int pg0 = pTile + tx * 8;
            if (pg0 < PP) {   // PP % 8 == 0: float4 pairs fully valid or fully out
                float4 s0 = {acc[0][j], acc[1][j], acc[2][j], acc[3][j]};
                float4 s1 = {acc[4][j], acc[5][j], acc[6][j], acc[7][j]};
                *(float4*)&sm2T[(long)kg * PP + pg0]     = s0;
                *(float4*)&sm2T[(long)kg * PP + pg0 + 4] = s1;
            }
        }
    }
}

// ---------------------------------------------------------------------------
// Kernel 3: per-k LSD radix sort (4 x 8-bit), zero per-thread persistent
// state; fused next-pass histograms, fused final dot, wave-shuffle scan.
// ---------------------------------------------------------------------------
#define WAVES  16
#define WCHUNK 1536             // 64 lanes * 24 iters

__device__ __forceinline__ unsigned long long matchany9(unsigned d) {
    unsigned long long m = ~0ull;
#pragma unroll
    for (int b = 0; b < 9; ++b) {
        unsigned bit = (d >> b) & 1u;
        unsigned long long bal = __ballot(bit);
        m &= bit ? bal : ~bal;
    }
    return m;
}

// counts in cntC -> stable scatter offsets in cntC; cntZ (if non-null) zeroed.
__device__ __forceinline__ void scan_hist(unsigned* cntC, unsigned* cntZ,
                                          unsigned* tot, int tid) {
    if (tid < 256) {            // exclusive prefix across waves, per digit
        unsigned run = 0;
        for (int w = 0; w < WAVES; ++w) {
            unsigned t = cntC[w * 256 + tid];
            cntC[w * 256 + tid] = run;
            run += t;
        }
        tot[tid] = run;
    }
    __syncthreads();
    if (tid < 64) {             // inclusive scan of tot[256], 4 bins/lane
        unsigned t0 = tot[tid * 4], t1 = tot[tid * 4 + 1];
        unsigned t2 = tot[tid * 4 + 2], t3 = tot[tid * 4 + 3];
        unsigned s = t0 + t1 + t2 + t3;
        unsigned sc = s;
#pragma unroll
        for (int off = 1; off < 64; off <<= 1) {
            unsigned o = (unsigned)__shfl_up((int)sc, off, 64);
            if (tid >= off) sc += o;
        }
        unsigned ex = sc - s;
        tot[tid * 4]     = ex + t0;
        tot[tid * 4 + 1] = ex + t0 + t1;
        tot[tid * 4 + 2] = ex + t0 + t1 + t2;
        tot[tid * 4 + 3] = ex + s;
    } else if (cntZ) {
        for (int i = tid - 64; i < WAVES * 256; i += 1024 - 64) cntZ[i] = 0;
    }
    __syncthreads();
    for (int i = tid; i < WAVES * 256; i += 1024) {
        int d = i & 255;
        unsigned db = (d == 0) ? 0u : tot[d - 1];
        cntC[i] += db;
    }
    __syncthreads();
}

__global__ __launch_bounds__(1024) void k_sort(
    float* sm2T,              // 181 x PP (row k read as pass-0 source)
    unsigned* bufA,           // 181 x PP scratch (overlays dead vec)
    const float* __restrict__ WdOut,  // 181 x PP
    float* __restrict__ out)          // 181
{
    __shared__ unsigned keysL[PP];          // 95.2 KiB
    __shared__ unsigned cntA[WAVES * 256];  // 16 KiB
    __shared__ unsigned cntB[WAVES * 256];  // 16 KiB
    __shared__ unsigned tot[256];
    __shared__ float red[WAVES];

    const int tid  = threadIdx.x;
    const int wave = tid >> 6;
    const int lane = tid & 63;
    const int k    = blockIdx.x;

    const unsigned* rowU = (const unsigned*)sm2T + (long)k * PP;
    unsigned* bA         = bufA + (long)k * PP;
    const float* wrow    = WdOut + (long)k * PP;

    const int base_idx = wave * WCHUNK + lane;
    const int wbase = wave * 256;
    const unsigned long long lt_mask = (1ull << lane) - 1ull;

// scatter pass: compute dest; optionally write LDS/global; optionally count
// next digit into CNTN; optionally accumulate the final dot.
#define SCATTER(SH, ENC, SRC_LDS, GSRC, DST_LDS, GDST, CNT, DO_NEXT, NSH, CNTN, DO_DOT) \
  for (int j = 0; j < 24; ++j) {                                               \
    int idx = base_idx + j * 64;                                               \
    bool valid = (idx < PP);                                                   \
    unsigned u = 0u;                                                           \
    if (valid) u = (SRC_LDS) ? keysL[idx] : (GSRC)[idx];                       \
    if (ENC) u = (u & 0x80000000u) ? ~u : (u | 0x80000000u);                   \
    unsigned d9 = ((u >> (SH)) & 255u) | (valid ? 0u : 256u);                  \
    unsigned long long mm = matchany9(d9);                                     \
    if (valid) {                                                               \
      int leader = __ffsll(mm) - 1;                                            \
      unsigned myrank = (unsigned)__popcll(mm & lt_mask);                      \
      unsigned old = 0;                                                        \
      if (lane == leader)                                                      \
        old = atomicAdd(&(CNT)[wbase + (d9 & 255u)], (unsigned)__popcll(mm));  \
      old = (unsigned)__shfl((int)old, leader, 64);                            \
      unsigned dest = old + myrank;                                            \
      if (DO_DOT) {                                                            \
        unsigned raw = (u & 0x80000000u) ? (u & 0x7FFFFFFFu) : ~u;             \
        local += wrow[dest] * __uint_as_float(raw);                            \
      } else {                                                                 \
        if (DST_LDS) keysL[dest] = u; else (GDST)[dest] = u;                   \
      }                                                                        \
      if (DO_NEXT) {                                                           \
        unsigned nd = (u >> (NSH)) & 255u;                                     \
        unsigned dw = dest / WCHUNK;                                           \
        atomicAdd(&(CNTN)[dw * 256 + nd], 1u);                                 \
      }                                                                        \
    }                                                                          \
  }                                                                            \
  __syncthreads();

    float local = 0.f;

    // pass 0 count (standalone)
    for (int i = tid; i < WAVES * 256; i += 1024) cntA[i] = 0;
    __syncthreads();
    for (int j = 0; j < 24; ++j) {
        int idx = base_idx + j * 64;
        if (idx < PP) {
            unsigned u = rowU[idx];
            u = (u & 0x80000000u) ? ~u : (u | 0x80000000u);
            atomicAdd(&cntA[wbase + (u & 255u)], 1u);
        }
    }
    __syncthreads();

    scan_hist(cntA, cntB, tot, tid);
    SCATTER(0,  true,  false, rowU, true,  bA, cntA, true,  8,  cntB, false)  // G->LDS
    scan_hist(cntB, cntA, tot, tid);
    SCATTER(8,  false, true,  rowU, false, bA, cntB, true,  16, cntA, false)  // LDS->G
    scan_hist(cntA, cntB, tot, tid);
    SCATTER(16, false, false, bA,   true,  bA, cntA, true,  24, cntB, false)  // G->LDS
    scan_hist(cntB, (unsigned*)0, tot, tid);
    SCATTER(24, false, true,  rowU, false, bA, cntB, false, 0,  cntA, true)   // LDS->dot
#undef SCATTER

    // block reduction of local
#pragma unroll
    for (int off = 32; off > 0; off >>= 1)
        local += __shfl_down(local, off, 64);
    if (lane == 0) red[wave] = local;
    __syncthreads();
    if (tid < WAVES) {
        float x = red[tid];
#pragma unroll
        for (int off = 8; off > 0; off >>= 1)
            x += __shfl_down(x, off, 64);
        if (tid == 0) out[k] = x;
    }
}

// ---------------------------------------------------------------------------
extern "C" void kernel_launch(void* const* d_in, const int* in_sizes, int n_in,
                              void* d_out, int out_size, void* d_ws, size_t ws_size,
                              hipStream_t stream) {
    const float* M      = (const float*)d_in[0];
    const float* Ws_in  = (const float*)d_in[1];
    const float* Wd_in  = (const float*)d_in[2];
    const float* Ws_out = (const float*)d_in[3];
    const float* Wd_out = (const float*)d_in[4];
    float* out = (float*)d_out;

    float* vec  = (float*)d_ws;                    // PP*VLD floats = 18.7 MB
    float* sm2T = vec + (size_t)PP * VLD;          // KK*PP floats  = 17.6 MB
    // k_sort scratch overlays vec (dead after k_gemm)
    unsigned* bufA = (unsigned*)d_ws;

    k_inner<<<1536, 256, 0, stream>>>(M, Ws_in, Wd_in, vec);

    dim3 g2((PP + GBP - 1) / GBP, (KK + GBK - 1) / GBK);
    k_gemm<<<g2, 256, 0, stream>>>(vec, Ws_out, sm2T);

    k_sort<<<KK, 1024, 0, stream>>>(sm2T, bufA, Wd_out, out);
}

// Round 11
// 293.462 us; speedup vs baseline: 5.0471x; 1.0351x over previous
//
#include <hip/hip_runtime.h>
#include <hip/hip_bf16.h>

#define DIMK 3
#define NPTS 30
#define KK   181
#define PP   24360
#define DEMB 190
#define VLD  192   // padded vec row stride (floats)

// ---------------------------------------------------------------------------
// Kernel 1: per-permutation inner embed -> vec (PP x VLD)
// Round-11: instruction diet. Gs rows padded to 32 words -> ds_read_b128
// (24 reads vs 90 b32); exclusion test via bitmask bfe (1 instr vs ~5);
// Wd dot via 7 ds_read_b128 at stride 28 (lane-varying k, conflict-free).
// grid=1280 (exactly 5 blocks/CU at launch_bounds(256,5); LDS 27.6KB x5 =
// 138KB). Per-chunk stream counts {1707,1707,1706} keep coverage exact.
// ---------------------------------------------------------------------------
__global__ __launch_bounds__(256, 5) void k_inner(
    const float* __restrict__ M,      // 3 x 30
    const float* __restrict__ Ws_in,  // 181 x 3
    const float* __restrict__ Wd_in,  // 181 x 27
    float* __restrict__ vec)          // PP x VLD
{
    __shared__ float Gs[NPTS * 32];     // rows padded to 32 (3.84 KB)
    __shared__ float WsS[192 * 3];      // zero-padded (2.3 KB)
    __shared__ float WdS[192 * 28];     // stride 28, zero-padded (21.5 KB)

    const int tid = threadIdx.x;

    for (int i = tid; i < 192 * 3; i += 256) WsS[i] = (i < KK * 3) ? Ws_in[i] : 0.f;
    for (int i = tid; i < 192 * 28; i += 256) {
        int k = i / 28, m = i - k * 28;
        WdS[i] = (k < KK && m < 27) ? Wd_in[k * 27 + m] : 0.f;
    }
    for (int e = tid; e < NPTS * 32; e += 256) {
        int a = e >> 5, b = e & 31;
        Gs[e] = (b < NPTS)
            ? (M[a] * M[b] + M[NPTS + a] * M[NPTS + b] + M[2 * NPTS + a] * M[2 * NPTS + b])
            : 0.f;
    }
    __syncthreads();

    const int wave = tid >> 6;
    const int lane = tid & 63;
    const int wid = blockIdx.x * 4 + wave;    // 0..5119
    const int chunk = wid % 3;
    const int pstream = wid / 3;              // 0..1706 (chunk 2: 0..1705)
    const int nstream = (chunk == 2) ? 1706 : 1707;
    const int k = chunk * 64 + lane;          // 0..191

    const float INF = __builtin_inff();
    const bool kvalid = (k < KK);
    const float w0 = WsS[k * 3 + 0];
    const float w1 = WsS[k * 3 + 1];
    const float w2 = WsS[k * 3 + 2];
    const float* wd = WdS + k * 28;

    for (int p = pstream; p < PP; p += nstream) {
        // factorial-number-system decode of itertools.permutations(range(30),3)
        int i0 = p / 812;            // 812 = 29*28
        int r  = p - i0 * 812;
        int i1 = r / 28;
        int i2 = r - i1 * 28;
        int c0 = i0;
        int c1 = i1 + (i1 >= c0 ? 1 : 0);
        int lo = min(c0, c1), hi = max(c0, c1);
        int c2 = i2;
        if (c2 >= lo) c2++;
        if (c2 >= hi) c2++;

        float* vrow = vec + (long)p * VLD;

        if (chunk == 0 && lane < 9) {
            int i = lane / 3, j = lane % 3;
            int ci = (i == 0) ? c0 : ((i == 1) ? c1 : c2);
            int cj = (j == 0) ? c0 : ((j == 1) ? c1 : c2);
            vrow[lane] = Gs[(ci << 5) + cj];
        }

        const float* g0 = Gs + (c0 << 5);
        const float* g1 = Gs + (c1 << 5);
        const float* g2 = Gs + (c2 << 5);
        const unsigned xmask = (1u << c0) | (1u << c1) | (1u << c2);

        float v[32];
#pragma unroll
        for (int q = 0; q < 8; ++q) {
            float4 x0 = *(const float4*)&g0[q * 4];
            float4 x1 = *(const float4*)&g1[q * 4];
            float4 x2 = *(const float4*)&g2[q * 4];
            int j0 = q * 4;
            if (j0 + 0 < NPTS) { float val = w0 * x0.x + w1 * x1.x + w2 * x2.x;
                v[j0 + 0] = ((xmask >> (j0 + 0)) & 1u) ? INF : val; }
            if (j0 + 1 < NPTS) { float val = w0 * x0.y + w1 * x1.y + w2 * x2.y;
                v[j0 + 1] = ((xmask >> (j0 + 1)) & 1u) ? INF : val; }
            if (j0 + 2 < NPTS) { float val = w0 * x0.z + w1 * x1.z + w2 * x2.z;
                v[j0 + 2] = ((xmask >> (j0 + 2)) & 1u) ? INF : val; }
            if (j0 + 3 < NPTS) { float val = w0 * x0.w + w1 * x1.w + w2 * x2.w;
                v[j0 + 3] = ((xmask >> (j0 + 3)) & 1u) ? INF : val; }
        }
        v[30] = INF;
        v[31] = INF;

        // Batcher odd-even mergesort, n=32, ascending (191 compare-exchanges)
#pragma unroll
        for (int pw = 1; pw < 32; pw <<= 1) {
#pragma unroll
            for (int kk = pw; kk >= 1; kk >>= 1) {
#pragma unroll
                for (int j = kk % pw; j + kk < 32; j += 2 * kk) {
#pragma unroll
                    for (int i = 0; i < kk; ++i) {
                        int a = i + j, b = i + j + kk;
                        if (a / (pw * 2) == b / (pw * 2)) {
                            float x = v[a], y = v[b];
                            v[a] = fminf(x, y);
                            v[b] = fmaxf(x, y);
                        }
                    }
                }
            }
        }

        if (kvalid) {
            v[27] = 0.f;   // slot 27 is always INF (5 poisons); wd[27]=0 pad
            float emb = 0.f;
#pragma unroll
            for (int q = 0; q < 7; ++q) {
                float4 w4 = *(const float4*)&wd[q * 4];
                emb += w4.x * v[q * 4] + w4.y * v[q * 4 + 1]
                     + w4.z * v[q * 4 + 2] + w4.w * v[q * 4 + 3];
            }
            vrow[9 + k] = emb;
        } else if (k < 183) {
            vrow[9 + k] = 0.f;   // pad entries 190,191 (k_gemm reads them)
        }
    }
}

// ---------------------------------------------------------------------------
// Kernel 2: sm2T[k][p] = dot(vec[p][0:190], Ws_out[k][0:190])
// Round-11: double-buffered LDS chunks + REGISTER-BATCHED staging (all 18
// global loads issued before any LDS store -> one memory latency per chunk,
// overlapped with compute of the previous chunk). One barrier per chunk.
// ---------------------------------------------------------------------------
#define GBP 128
#define GBK 64
#define GDC 48
#define LDA 132   // As row stride (128 + 4, keeps 16B alignment)
#define LDB 68    // Bs row stride (64 + 4)

__global__ __launch_bounds__(256, 4) void k_gemm(
    const float* __restrict__ vec,    // PP x VLD
    const float* __restrict__ Wout,   // 181 x 190
    float* __restrict__ sm2T)         // 181 x PP
{
    __shared__ float As[2][GDC * LDA];   // 2 x 25.3 KB, [d][pl]
    __shared__ float Bs[2][GDC * LDB];   // 2 x 13 KB,   [d][kl]

    const int tid = threadIdx.x;
    const int pTile = blockIdx.x * GBP;
    const int kTile = blockIdx.y * GBK;
    const int tx = tid & 15;   // p dir, 8 p's each
    const int ty = tid >> 4;   // k dir, 4 k's each

    float acc[8][4];
#pragma unroll
    for (int i = 0; i < 8; ++i)
#pragma unroll
        for (int j = 0; j < 4; ++j) acc[i][j] = 0.f;

    float4 ta[6];
    float  tb[12];

#define LOADCH(DB) do {                                                        \
    _Pragma("unroll")                                                          \
    for (int it = 0; it < 6; ++it) {                                           \
        int e = tid + it * 256; int q = e % 12, pl = e / 12;                   \
        int pg = pTile + pl;                                                   \
        ta[it] = make_float4(0.f, 0.f, 0.f, 0.f);                              \
        if (pg < PP) ta[it] = *(const float4*)&vec[(long)pg * VLD + (DB) + q * 4]; \
    }                                                                          \
    _Pragma("unroll")                                                          \
    for (int it = 0; it < 12; ++it) {                                          \
        int e = tid + it * 256; int d = e % GDC, kl = e / GDC;                 \
        int kg = kTile + kl, dg = (DB) + d;                                    \
        tb[it] = (kg < KK && dg < DEMB) ? Wout[kg * DEMB + dg] : 0.f;          \
    }                                                                          \
} while (0)

#define STORECH(B) do {                                                        \
    _Pragma("unroll")                                                          \
    for (int it = 0; it < 6; ++it) {                                           \
        int e = tid + it * 256; int q = e % 12, pl = e / 12; int d0 = q * 4;   \
        As[B][(d0 + 0) * LDA + pl] = ta[it].x;                                 \
        As[B][(d0 + 1) * LDA + pl] = ta[it].y;                                 \
        As[B][(d0 + 2) * LDA + pl] = ta[it].z;                                 \
        As[B][(d0 + 3) * LDA + pl] = ta[it].w;                                 \
    }                                                                          \
    _Pragma("unroll")                                                          \
    for (int it = 0; it < 12; ++it) {                                          \
        int e = tid + it * 256; int d = e % GDC, kl = e / GDC;                 \
        Bs[B][d * LDB + kl] = tb[it];                                          \
    }                                                                          \
} while (0)

    LOADCH(0);
    STORECH(0);

    for (int ch = 0; ch < 4; ++ch) {
        const int cur = ch & 1;
        __syncthreads();
        if (ch < 3) LOADCH((ch + 1) * GDC);

        for (int d = 0; d < GDC; ++d) {
            float4 a0 = *(const float4*)&As[cur][d * LDA + tx * 8];
            float4 a1 = *(const float4*)&As[cur][d * LDA + tx * 8 + 4];
            float4 b0 = *(const float4*)&Bs[cur][d * LDB + ty * 4];
            float a[8] = {a0.x, a0.y, a0.z, a0.w, a1.x, a1.y, a1.z, a1.w};
            float b[4] = {b0.x, b0.y, b0.z, b0.w};
#pragma unroll
            for (int i = 0; i < 8; ++i)
#pragma unroll
                for (int j = 0; j < 4; ++j) acc[i][j] += a[i] * b[j];
        }

        if (ch < 3) STORECH(cur ^ 1);
    }
#undef LOADCH
#undef STORECH

#pragma unroll
    for (int j = 0; j < 4; ++j) {
        int kg = kTile + ty * 4 + j;
        if (kg < KK) {
            int pg0 = pTile + tx * 8;
            if (pg0 < PP) {   // PP % 8 == 0: float4 pairs fully valid or fully out
                float4 s0 = {acc[0][j], acc[1][j], acc[2][j], acc[3][j]};
                float4 s1 = {acc[4][j], acc[5][j], acc[6][j], acc[7][j]};
                *(float4*)&sm2T[(long)kg * PP + pg0]     = s0;
                *(float4*)&sm2T[(long)kg * PP + pg0 + 4] = s1;
            }
        }
    }
}

// ---------------------------------------------------------------------------
// Kernel 3: per-k LSD radix sort (4 x 8-bit), zero per-thread persistent
// state; fused next-pass histograms, fused final dot, wave-shuffle scan.
// (frozen from round 8/10 — 103 us)
// ---------------------------------------------------------------------------
#define WAVES  16
#define WCHUNK 1536             // 64 lanes * 24 iters

__device__ __forceinline__ unsigned long long matchany9(unsigned d) {
    unsigned long long m = ~0ull;
#pragma unroll
    for (int b = 0; b < 9; ++b) {
        unsigned bit = (d >> b) & 1u;
        unsigned long long bal = __ballot(bit);
        m &= bit ? bal : ~bal;
    }
    return m;
}

// counts in cntC -> stable scatter offsets in cntC; cntZ (if non-null) zeroed.
__device__ __forceinline__ void scan_hist(unsigned* cntC, unsigned* cntZ,
                                          unsigned* tot, int tid) {
    if (tid < 256) {            // exclusive prefix across waves, per digit
        unsigned run = 0;
        for (int w = 0; w < WAVES; ++w) {
            unsigned t = cntC[w * 256 + tid];
            cntC[w * 256 + tid] = run;
            run += t;
        }
        tot[tid] = run;
    }
    __syncthreads();
    if (tid < 64) {             // inclusive scan of tot[256], 4 bins/lane
        unsigned t0 = tot[tid * 4], t1 = tot[tid * 4 + 1];
        unsigned t2 = tot[tid * 4 + 2], t3 = tot[tid * 4 + 3];
        unsigned s = t0 + t1 + t2 + t3;
        unsigned sc = s;
#pragma unroll
        for (int off = 1; off < 64; off <<= 1) {
            unsigned o = (unsigned)__shfl_up((int)sc, off, 64);
            if (tid >= off) sc += o;
        }
        unsigned ex = sc - s;
        tot[tid * 4]     = ex + t0;
        tot[tid * 4 + 1] = ex + t0 + t1;
        tot[tid * 4 + 2] = ex + t0 + t1 + t2;
        tot[tid * 4 + 3] = ex + s;
    } else if (cntZ) {
        for (int i = tid - 64; i < WAVES * 256; i += 1024 - 64) cntZ[i] = 0;
    }
    __syncthreads();
    for (int i = tid; i < WAVES * 256; i += 1024) {
        int d = i & 255;
        unsigned db = (d == 0) ? 0u : tot[d - 1];
        cntC[i] += db;
    }
    __syncthreads();
}

__global__ __launch_bounds__(1024) void k_sort(
    float* sm2T,              // 181 x PP (row k read as pass-0 source)
    unsigned* bufA,           // 181 x PP scratch (overlays dead vec)
    const float* __restrict__ WdOut,  // 181 x PP
    float* __restrict__ out)          // 181
{
    __shared__ unsigned keysL[PP];          // 95.2 KiB
    __shared__ unsigned cntA[WAVES * 256];  // 16 KiB
    __shared__ unsigned cntB[WAVES * 256];  // 16 KiB
    __shared__ unsigned tot[256];
    __shared__ float red[WAVES];

    const int tid  = threadIdx.x;
    const int wave = tid >> 6;
    const int lane = tid & 63;
    const int k    = blockIdx.x;

    const unsigned* rowU = (const unsigned*)sm2T + (long)k * PP;
    unsigned* bA         = bufA + (long)k * PP;
    const float* wrow    = WdOut + (long)k * PP;

    const int base_idx = wave * WCHUNK + lane;
    const int wbase = wave * 256;
    const unsigned long long lt_mask = (1ull << lane) - 1ull;

// scatter pass: compute dest; optionally write LDS/global; optionally count
// next digit into CNTN; optionally accumulate the final dot.
#define SCATTER(SH, ENC, SRC_LDS, GSRC, DST_LDS, GDST, CNT, DO_NEXT, NSH, CNTN, DO_DOT) \
  for (int j = 0; j < 24; ++j) {                                               \
    int idx = base_idx + j * 64;                                               \
    bool valid = (idx < PP);                                                   \
    unsigned u = 0u;                                                           \
    if (valid) u = (SRC_LDS) ? keysL[idx] : (GSRC)[idx];                       \
    if (ENC) u = (u & 0x80000000u) ? ~u : (u | 0x80000000u);                   \
    unsigned d9 = ((u >> (SH)) & 255u) | (valid ? 0u : 256u);                  \
    unsigned long long mm = matchany9(d9);                                     \
    if (valid) {                                                               \
      int leader = __ffsll(mm) - 1;                                            \
      unsigned myrank = (unsigned)__popcll(mm & lt_mask);                      \
      unsigned old = 0;                                                        \
      if (lane == leader)                                                      \
        old = atomicAdd(&(CNT)[wbase + (d9 & 255u)], (unsigned)__popcll(mm));  \
      old = (unsigned)__shfl((int)old, leader, 64);                            \
      unsigned dest = old + myrank;                                            \
      if (DO_DOT) {                                                            \
        unsigned raw = (u & 0x80000000u) ? (u & 0x7FFFFFFFu) : ~u;             \
        local += wrow[dest] * __uint_as_float(raw);                            \
      } else {                                                                 \
        if (DST_LDS) keysL[dest] = u; else (GDST)[dest] = u;                   \
      }                                                                        \
      if (DO_NEXT) {                                                           \
        unsigned nd = (u >> (NSH)) & 255u;                                     \
        unsigned dw = dest / WCHUNK;                                           \
        atomicAdd(&(CNTN)[dw * 256 + nd], 1u);                                 \
      }                                                                        \
    }                                                                          \
  }                                                                            \
  __syncthreads();

    float local = 0.f;

    // pass 0 count (standalone)
    for (int i = tid; i < WAVES * 256; i += 1024) cntA[i] = 0;
    __syncthreads();
    for (int j = 0; j < 24; ++j) {
        int idx = base_idx + j * 64;
        if (idx < PP) {
            unsigned u = rowU[idx];
            u = (u & 0x80000000u) ? ~u : (u | 0x80000000u);
            atomicAdd(&cntA[wbase + (u & 255u)], 1u);
        }
    }
    __syncthreads();

    scan_hist(cntA, cntB, tot, tid);
    SCATTER(0,  true,  false, rowU, true,  bA, cntA, true,  8,  cntB, false)  // G->LDS
    scan_hist(cntB, cntA, tot, tid);
    SCATTER(8,  false, true,  rowU, false, bA, cntB, true,  16, cntA, false)  // LDS->G
    scan_hist(cntA, cntB, tot, tid);
    SCATTER(16, false, false, bA,   true,  bA, cntA, true,  24, cntB, false)  // G->LDS
    scan_hist(cntB, (unsigned*)0, tot, tid);
    SCATTER(24, false, true,  rowU, false, bA, cntB, false, 0,  cntA, true)   // LDS->dot
#undef SCATTER

    // block reduction of local
#pragma unroll
    for (int off = 32; off > 0; off >>= 1)
        local += __shfl_down(local, off, 64);
    if (lane == 0) red[wave] = local;
    __syncthreads();
    if (tid < WAVES) {
        float x = red[tid];
#pragma unroll
        for (int off = 8; off > 0; off >>= 1)
            x += __shfl_down(x, off, 64);
        if (tid == 0) out[k] = x;
    }
}

// ---------------------------------------------------------------------------
extern "C" void kernel_launch(void* const* d_in, const int* in_sizes, int n_in,
                              void* d_out, int out_size, void* d_ws, size_t ws_size,
                              hipStream_t stream) {
    const float* M      = (const float*)d_in[0];
    const float* Ws_in  = (const float*)d_in[1];
    const float* Wd_in  = (const float*)d_in[2];
    const float* Ws_out = (const float*)d_in[3];
    const float* Wd_out = (const float*)d_in[4];
    float* out = (float*)d_out;

    float* vec  = (float*)d_ws;                    // PP*VLD floats = 18.7 MB
    float* sm2T = vec + (size_t)PP * VLD;          // KK*PP floats  = 17.6 MB
    // k_sort scratch overlays vec (dead after k_gemm)
    unsigned* bufA = (unsigned*)d_ws;

    k_inner<<<1280, 256, 0, stream>>>(M, Ws_in, Wd_in, vec);

    dim3 g2((PP + GBP - 1) / GBP, (KK + GBK - 1) / GBK);
    k_gemm<<<g2, 256, 0, stream>>>(vec, Ws_out, sm2T);

    k_sort<<<KK, 1024, 0, stream>>>(sm2T, bufA, Wd_out, out);
}